// Round 5
// baseline (317.117 us; speedup 1.0000x reference)
//
#include <hip/hip_runtime.h>
#include <hip/hip_bf16.h>
#include <math.h>

typedef __attribute__((ext_vector_type(4))) float f32x4;
typedef __attribute__((ext_vector_type(16))) float f32x16;
typedef __attribute__((ext_vector_type(8))) short bf16x8;
typedef __attribute__((ext_vector_type(4))) unsigned int u32x4;

#define DEV __device__ __forceinline__
#define MFMA16 __builtin_amdgcn_mfma_f32_16x16x32_bf16
#define MFMA32 __builtin_amdgcn_mfma_f32_32x32x16_bf16
#define SBAR __builtin_amdgcn_s_barrier()
#define SCHED0 __builtin_amdgcn_sched_barrier(0)

constexpr int S      = 2048;
constexpr int DMODEL = 1024;
constexpr int HD     = 64;
constexpr int MROWS  = 4 * 2048;   // B*S = 8192

DEV unsigned short f2bf(float f) {
  union { float f; unsigned int u; } v; v.f = f;
  unsigned int u = v.u;
  unsigned int r = u + 0x7fffu + ((u >> 16) & 1u);
  return (unsigned short)(r >> 16);
}

DEV unsigned int pkbf(float lo, float hi) {
  __hip_bfloat162 h = __float22bfloat162_rn(float2{lo, hi});
  union { __hip_bfloat162 h; unsigned int u; } c; c.h = h;
  return c.u;
}

DEV void gload_lds16(const void* g, void* l) {
  __builtin_amdgcn_global_load_lds(
      (const __attribute__((address_space(1))) unsigned int*)g,
      (__attribute__((address_space(3))) unsigned int*)l, 16, 0, 0);
}

// ---------------- fp32 -> bf16 convert (x) ----------------
__global__ __launch_bounds__(256) void k_conv(const float* __restrict__ in,
                                              unsigned short* __restrict__ out) {
  int i = blockIdx.x * 256 + threadIdx.x;
  float4 v = ((const float4*)in)[i];
  ushort4 o;
  o.x = f2bf(v.x); o.y = f2bf(v.y); o.z = f2bf(v.z); o.w = f2bf(v.w);
  ((ushort4*)out)[i] = o;
}

// ---------------- transpose + convert weights: Wt[n][k] = W[k][n] ----------------
__global__ __launch_bounds__(256) void k_transpose(const float* __restrict__ W,
                                                   unsigned short* __restrict__ Wt) {
  __shared__ float tile[32][33];
  int n0 = blockIdx.x * 32, k0 = blockIdx.y * 32;
  int tx = threadIdx.x, ty = threadIdx.y;  // (32,8)
#pragma unroll
  for (int j = 0; j < 4; ++j)
    tile[ty + j * 8][tx] = W[(size_t)(k0 + ty + j * 8) * DMODEL + n0 + tx];
  __syncthreads();
#pragma unroll
  for (int j = 0; j < 4; ++j)
    Wt[(size_t)(n0 + ty + j * 8) * DMODEL + k0 + tx] = f2bf(tile[tx][ty + j * 8]);
}

// ---------------- counted-vmcnt double-buffered GEMM (T3+T4+T5+T2) ----------------
// BM=256, BN=128, BK=64, 512 thr = 8 waves (4M x 2N), per-wave 64x64 output.
// EPI=0: scatter bf16 to Q/K/V (B,H,S,HD); Q pre-scaled by 0.125/ln2 (exp2 trick).
// EPI=1: fp32 out = acc + bo[n].
template<int NBX, int EPI>
__global__ __launch_bounds__(512, 2) void k_gemm8(const unsigned short* __restrict__ A,
                                                  const unsigned short* __restrict__ Bt,
                                                  unsigned short* __restrict__ Qg,
                                                  unsigned short* __restrict__ Kg,
                                                  unsigned short* __restrict__ Vg,
                                                  const float* __restrict__ bo,
                                                  float* __restrict__ out) {
  __shared__ __align__(16) char lds[98304];
  const int tid = threadIdx.x, lane = tid & 63;
  const int wid = tid >> 6, wm = wid >> 1, wn = wid & 1;
  const int lq = lane & 15, lg = lane >> 4;
  const int flat = blockIdx.x;
  const int wg = (flat & 7) * (NBX * 4) + (flat >> 3);
  const int by = wg / NBX, bx = wg % NBX;
  const int m0 = by * 256, n0 = bx * 128;

  auto stage = [&](int kt, int buf) {
    char* dA = lds + buf * 49152;
    char* dB = dA + 32768;
    const unsigned short* gA = A + (size_t)m0 * DMODEL + kt * 64;
    const unsigned short* gB = Bt + (size_t)n0 * DMODEL + kt * 64;
#pragma unroll
    for (int i = 0; i < 4; ++i) {
      int c = tid + i * 512; int r = c >> 3, cc = c & 7;
      gload_lds16(gA + (size_t)r * DMODEL + ((cc ^ (r & 7)) << 3), dA + c * 16);
    }
#pragma unroll
    for (int i = 0; i < 2; ++i) {
      int c = tid + i * 512; int r = c >> 3, cc = c & 7;
      gload_lds16(gB + (size_t)r * DMODEL + ((cc ^ (r & 7)) << 3), dB + c * 16);
    }
  };

  stage(0, 0);
  stage(1, 1);
  SCHED0;
  asm volatile("s_waitcnt vmcnt(6)" ::: "memory");
  SCHED0;
  SBAR;
  SCHED0;

  f32x4 acc[4][4] = {};
#pragma unroll 1
  for (int t = 0; t < 16; ++t) {
    const int cur = t & 1;
    const char* pA = lds + cur * 49152;
    const char* pB = pA + 32768;
    bf16x8 af[4][2], bf[4][2];
#pragma unroll
    for (int kk = 0; kk < 2; ++kk) {
#pragma unroll
      for (int mi = 0; mi < 4; ++mi) {
        int row = wm * 64 + mi * 16 + lq;
        af[mi][kk] = *(const bf16x8*)(pA + row * 128 + ((((kk << 2) + lg) ^ (row & 7)) << 4));
      }
#pragma unroll
      for (int ni = 0; ni < 4; ++ni) {
        int row = wn * 64 + ni * 16 + lq;
        bf[ni][kk] = *(const bf16x8*)(pB + row * 128 + ((((kk << 2) + lg) ^ (row & 7)) << 4));
      }
    }
    asm volatile("s_waitcnt lgkmcnt(0)" ::: "memory");
    SCHED0;
    SBAR;
    SCHED0;
    if (t < 14) stage(t + 2, cur);
    __builtin_amdgcn_s_setprio(1);
#pragma unroll
    for (int kk = 0; kk < 2; ++kk)
#pragma unroll
      for (int mi = 0; mi < 4; ++mi)
#pragma unroll
        for (int ni = 0; ni < 4; ++ni)
          acc[mi][ni] = MFMA16(af[mi][kk], bf[ni][kk], acc[mi][ni], 0, 0, 0);
    __builtin_amdgcn_s_setprio(0);
    SCHED0;
    if (t < 14) {
      asm volatile("s_waitcnt vmcnt(6)" ::: "memory");
    } else if (t == 14) {
      asm volatile("s_waitcnt vmcnt(0)" ::: "memory");
    }
    SCHED0;
    SBAR;
    SCHED0;
  }

  if (EPI == 0) {
#pragma unroll
    for (int mi = 0; mi < 4; ++mi)
#pragma unroll
      for (int ni = 0; ni < 4; ++ni) {
        int n = n0 + wn * 64 + ni * 16 + lq;
        int widx = n >> 10, nn = n & 1023;
        int h = nn >> 6, d = nn & 63;
        unsigned short* dst = (widx == 0) ? Qg : ((widx == 1) ? Kg : Vg);
        // Q carries 0.125 * (1/ln2): scores come out in log2 units -> exp2 in attn
        float scale = (widx == 0) ? 0.18033688f : 1.0f;
#pragma unroll
        for (int r = 0; r < 4; ++r) {
          int m = m0 + wm * 64 + mi * 16 + lg * 4 + r;
          int b_ = m >> 11, s_ = m & 2047;
          dst[(size_t)((b_ * 16 + h) * 2048 + s_) * HD + d] = f2bf(acc[mi][ni][r] * scale);
        }
      }
  } else {
#pragma unroll
    for (int mi = 0; mi < 4; ++mi)
#pragma unroll
      for (int ni = 0; ni < 4; ++ni) {
        int n = n0 + wn * 64 + ni * 16 + lq;
        float bv = bo[n];
#pragma unroll
        for (int r = 0; r < 4; ++r) {
          int m = m0 + wm * 64 + mi * 16 + lg * 4 + r;
          out[(size_t)m * DMODEL + n] = acc[mi][ni][r] + bv;
        }
      }
  }
}

// ---------------- causal flash attention: swapped-QK^T, in-register softmax ----------------
// 4 waves x 32 q-rows = 128-row sub-blocks; grid (8,64) = 512 blocks = 2/CU, all resident.
// Block bx: pair pr = bx>>1, sub = bx&1. Uniform 36 tile-iters. Scores in log2 units.
__global__ __launch_bounds__(256, 4) void k_attn(const unsigned short* __restrict__ Qg,
                                                 const unsigned short* __restrict__ Kg,
                                                 const unsigned short* __restrict__ Vg,
                                                 unsigned short* __restrict__ Ctx) {
  __shared__ __align__(16) char lds[32768];
  const int pr = blockIdx.x >> 1;     // 0..3
  const int sub = blockIdx.x & 1;     // 0..1
  const int bh = blockIdx.y;
  const int tid = threadIdx.x;
  const int lane = tid & 63, w = tid >> 6;   // w in 0..3
  const int lq5 = lane & 31, hi = lane >> 5;
  const size_t base = (size_t)bh * (S * HD);
  const int b = bh >> 4, h = bh & 15;

#pragma unroll 1
  for (int half = 0; half < 2; ++half) {
    const int Qb = half ? (7 - pr) : pr;
    const int q0w = Qb * 256 + sub * 128 + w * 32;
    const int tmax = 4 * Qb + 3;
    const int diag = q0w >> 6;

    bf16x8 qF[4];
#pragma unroll
    for (int dc = 0; dc < 4; ++dc)
      qF[dc] = *(const bf16x8*)(Qg + base + (size_t)(q0w + lq5) * HD + dc * 16 + hi * 8);

    f32x16 o0 = {}, o1 = {};
    float m_run = -INFINITY, l_run = 0.f;

    __syncthreads();
    // prologue: stage tile 0 into buf0 (256 threads -> 2 chunks each)
#pragma unroll
    for (int i = 0; i < 2; ++i) {
      int c = tid + i * 256;
      int row = c >> 3, cc = c & 7, scc = cc ^ (row & 7);
      gload_lds16(Kg + base + (size_t)row * HD + scc * 8, lds + c * 16);
    }
#pragma unroll
    for (int i = 0; i < 2; ++i) {
      int c = tid + i * 256;
      int krow = c >> 3, vcc = c & 7;
      bf16x8 vv = *(const bf16x8*)(Vg + base + (size_t)krow * HD + vcc * 8);
#pragma unroll
      for (int j = 0; j < 8; ++j) {
        int d = vcc * 8 + j;
        int fd = (d & 7) ^ ((d >> 3) & 7);
        *(unsigned short*)(lds + 16384 + d * 128 + (((krow >> 3) ^ fd) << 4) + (krow & 7) * 2) =
            (unsigned short)vv[j];
      }
    }
    __syncthreads();

#pragma unroll 1
    for (int t = 0; t <= tmax; ++t) {
      const int cur = t & 1, nxt = cur ^ 1;
      char* sK  = lds + cur * 8192;
      char* sVT = lds + 16384 + cur * 8192;
      const bool have_next = (t < tmax);
      bf16x8 vv[2];
      if (have_next) {   // T14: issue next-tile loads EARLY
#pragma unroll
        for (int i = 0; i < 2; ++i) {
          int c = tid + i * 256;
          int krow = c >> 3, vcc = c & 7;
          vv[i] = *(const bf16x8*)(Vg + base + (size_t)((t + 1) * 64 + krow) * HD + vcc * 8);
        }
#pragma unroll
        for (int i = 0; i < 2; ++i) {
          int c = tid + i * 256;
          int row = c >> 3, cc = c & 7, scc = cc ^ (row & 7);
          gload_lds16(Kg + base + (size_t)((t + 1) * 64 + row) * HD + scc * 8,
                      lds + nxt * 8192 + c * 16);
        }
      }
      const bool active = (t <= diag);
      if (active) {
        const bool isdiag = (t == diag);
        const int nkb = (isdiag && !(q0w & 32)) ? 1 : 2;
        f32x16 st0 = {}, st1 = {};
        __builtin_amdgcn_s_setprio(1);
#pragma unroll
        for (int dc = 0; dc < 4; ++dc) {
          int row = lq5;
          bf16x8 a0 = *(const bf16x8*)(sK + row * 128 + (((2 * dc + hi) ^ (row & 7)) << 4));
          st0 = MFMA32(a0, qF[dc], st0, 0, 0, 0);
        }
        if (nkb == 2) {
#pragma unroll
          for (int dc = 0; dc < 4; ++dc) {
            int row = 32 + lq5;
            bf16x8 a1 = *(const bf16x8*)(sK + row * 128 + (((2 * dc + hi) ^ (row & 7)) << 4));
            st1 = MFMA32(a1, qF[dc], st1, 0, 0, 0);
          }
        }
        __builtin_amdgcn_s_setprio(0);
        if (isdiag) {
          int qo = q0w + lq5 - t * 64;
          if (q0w & 32) {
#pragma unroll
            for (int r = 0; r < 16; ++r) {
              int key = 32 + (r & 3) + 8 * (r >> 2) + 4 * hi;
              st1[r] = (key > qo) ? -INFINITY : st1[r];
            }
          } else {
#pragma unroll
            for (int r = 0; r < 16; ++r) {
              int key = (r & 3) + 8 * (r >> 2) + 4 * hi;
              st0[r] = (key > qo) ? -INFINITY : st0[r];
            }
          }
        }
        float mx = st0[0];
#pragma unroll
        for (int r = 1; r < 16; ++r) mx = fmaxf(mx, st0[r]);
        if (nkb == 2) {
#pragma unroll
          for (int r = 0; r < 16; ++r) mx = fmaxf(mx, st1[r]);
        }
        mx = fmaxf(mx, __shfl_xor(mx, 32));
        bool need = !(mx <= m_run + 8.0f);
        if (__any(need)) {
          float mn = fmaxf(m_run, mx);
          float alpha = exp2f(m_run - mn);
          m_run = mn;
          l_run *= alpha;
#pragma unroll
          for (int r = 0; r < 16; ++r) { o0[r] *= alpha; o1[r] *= alpha; }
        }
        float rs[4] = {0.f, 0.f, 0.f, 0.f};
#pragma unroll
        for (int r = 0; r < 16; ++r) {
          float p = exp2f(st0[r] - m_run);
          st0[r] = p;
          rs[r & 3] += p;
        }
        if (nkb == 2) {
#pragma unroll
          for (int r = 0; r < 16; ++r) {
            float p = exp2f(st1[r] - m_run);
            st1[r] = p;
            rs[r & 3] += p;
          }
        }
        float rsum = (rs[0] + rs[1]) + (rs[2] + rs[3]);
        rsum += __shfl_xor(rsum, 32);
        l_run += rsum;
        {
          unsigned int wv[8];
#pragma unroll
          for (int j = 0; j < 8; ++j) wv[j] = pkbf(st0[2 * j], st0[2 * j + 1]);
          asm("v_permlane32_swap_b32 %0, %1" : "+v"(wv[0]), "+v"(wv[2]));
          asm("v_permlane32_swap_b32 %0, %1" : "+v"(wv[1]), "+v"(wv[3]));
          asm("v_permlane32_swap_b32 %0, %1" : "+v"(wv[4]), "+v"(wv[6]));
          asm("v_permlane32_swap_b32 %0, %1" : "+v"(wv[5]), "+v"(wv[7]));
          union { bf16x8 v; unsigned int u[4]; } fa, fb;
          fa.u[0] = wv[0]; fa.u[1] = wv[1]; fa.u[2] = wv[2]; fa.u[3] = wv[3];
          fb.u[0] = wv[4]; fb.u[1] = wv[5]; fb.u[2] = wv[6]; fb.u[3] = wv[7];
          __builtin_amdgcn_s_setprio(1);
#pragma unroll
          for (int kc = 0; kc < 2; ++kc) {
            bf16x8 bp = kc ? fb.v : fa.v;
            {
              int d = lq5, fd = (d & 7) ^ ((d >> 3) & 7);
              bf16x8 av = *(const bf16x8*)(sVT + d * 128 + (((kc * 2 + hi) ^ fd) << 4));
              o0 = MFMA32(av, bp, o0, 0, 0, 0);
            }
            {
              int d = 32 + lq5, fd = (d & 7) ^ ((d >> 3) & 7);
              bf16x8 av = *(const bf16x8*)(sVT + d * 128 + (((kc * 2 + hi) ^ fd) << 4));
              o1 = MFMA32(av, bp, o1, 0, 0, 0);
            }
          }
          __builtin_amdgcn_s_setprio(0);
        }
        if (nkb == 2) {
          unsigned int wv[8];
#pragma unroll
          for (int j = 0; j < 8; ++j) wv[j] = pkbf(st1[2 * j], st1[2 * j + 1]);
          asm("v_permlane32_swap_b32 %0, %1" : "+v"(wv[0]), "+v"(wv[2]));
          asm("v_permlane32_swap_b32 %0, %1" : "+v"(wv[1]), "+v"(wv[3]));
          asm("v_permlane32_swap_b32 %0, %1" : "+v"(wv[4]), "+v"(wv[6]));
          asm("v_permlane32_swap_b32 %0, %1" : "+v"(wv[5]), "+v"(wv[7]));
          union { bf16x8 v; unsigned int u[4]; } fa, fb;
          fa.u[0] = wv[0]; fa.u[1] = wv[1]; fa.u[2] = wv[2]; fa.u[3] = wv[3];
          fb.u[0] = wv[4]; fb.u[1] = wv[5]; fb.u[2] = wv[6]; fb.u[3] = wv[7];
          __builtin_amdgcn_s_setprio(1);
#pragma unroll
          for (int kc = 0; kc < 2; ++kc) {
            bf16x8 bp = kc ? fb.v : fa.v;
            {
              int d = lq5, fd = (d & 7) ^ ((d >> 3) & 7);
              bf16x8 av = *(const bf16x8*)(sVT + d * 128 + ((((2 + kc) * 2 + hi) ^ fd) << 4));
              o0 = MFMA32(av, bp, o0, 0, 0, 0);
            }
            {
              int d = 32 + lq5, fd = (d & 7) ^ ((d >> 3) & 7);
              bf16x8 av = *(const bf16x8*)(sVT + d * 128 + ((((2 + kc) * 2 + hi) ^ fd) << 4));
              o1 = MFMA32(av, bp, o1, 0, 0, 0);
            }
          }
          __builtin_amdgcn_s_setprio(0);
        }
      }
      if (have_next) {   // T14: write staged V LATE
        char* dVT = lds + 16384 + nxt * 8192;
#pragma unroll
        for (int i = 0; i < 2; ++i) {
          int c = tid + i * 256;
          int krow = c >> 3, vcc = c & 7;
#pragma unroll
          for (int j = 0; j < 8; ++j) {
            int d = vcc * 8 + j;
            int fd = (d & 7) ^ ((d >> 3) & 7);
            *(unsigned short*)(dVT + d * 128 + (((krow >> 3) ^ fd) << 4) + (krow & 7) * 2) =
                (unsigned short)vv[i][j];
          }
        }
      }
      __syncthreads();
    }

    __syncthreads();
    {
      float inv = 1.0f / l_run;
      char* slice = lds + w * 4096;
#pragma unroll
      for (int db = 0; db < 2; ++db)
#pragma unroll
        for (int j = 0; j < 8; ++j) {
          int d0 = (j & 1) * 2 + (j >> 1) * 8 + 4 * hi + 32 * db;
          float va = (db ? o1[2 * j] : o0[2 * j]) * inv;
          float vb = (db ? o1[2 * j + 1] : o0[2 * j + 1]) * inv;
          *(unsigned int*)(slice + lq5 * 128 + (((d0 >> 3) ^ (lq5 & 7)) << 4) + (d0 & 7) * 2) =
              pkbf(va, vb);
        }
      asm volatile("s_waitcnt lgkmcnt(0)" ::: "memory");
#pragma unroll
      for (int i = 0; i < 4; ++i) {
        int r = lane >> 1, cc = (lane & 1) * 4 + i;
        u32x4 v = *(const u32x4*)(slice + r * 128 + ((cc ^ (r & 7)) << 4));
        *(u32x4*)(Ctx + (size_t)(b * S + q0w + r) * DMODEL + h * HD + cc * 8) = v;
      }
    }
  }
}

extern "C" void kernel_launch(void* const* d_in, const int* in_sizes, int n_in,
                              void* d_out, int out_size, void* d_ws, size_t ws_size,
                              hipStream_t stream) {
  const float* x  = (const float*)d_in[0];
  const float* Wq = (const float*)d_in[1];
  const float* Wk = (const float*)d_in[2];
  const float* Wv = (const float*)d_in[3];
  const float* Wo = (const float*)d_in[4];
  const float* bo = (const float*)d_in[5];
  float* out = (float*)d_out;

  char* p = (char*)d_ws;
  unsigned short* xb  = (unsigned short*)p; p += (size_t)MROWS * DMODEL * 2;
  unsigned short* wt  = (unsigned short*)p; p += (size_t)3 * DMODEL * DMODEL * 2;
  unsigned short* wot = (unsigned short*)p; p += (size_t)DMODEL * DMODEL * 2;
  unsigned short* qg  = (unsigned short*)p; p += (size_t)MROWS * DMODEL * 2;
  unsigned short* kg  = (unsigned short*)p; p += (size_t)MROWS * DMODEL * 2;
  unsigned short* vg  = (unsigned short*)p; p += (size_t)MROWS * DMODEL * 2;
  unsigned short* ctx = (unsigned short*)p; p += (size_t)MROWS * DMODEL * 2;

  k_conv<<<(MROWS * DMODEL) / 1024, 256, 0, stream>>>(x, xb);
  dim3 tb(32, 8), tg(32, 32);
  k_transpose<<<tg, tb, 0, stream>>>(Wq, wt);
  k_transpose<<<tg, tb, 0, stream>>>(Wk, wt + (size_t)DMODEL * DMODEL);
  k_transpose<<<tg, tb, 0, stream>>>(Wv, wt + (size_t)2 * DMODEL * DMODEL);
  k_transpose<<<tg, tb, 0, stream>>>(Wo, wot);
  k_gemm8<24, 0><<<768, 512, 0, stream>>>(xb, wt, qg, kg, vg, nullptr, nullptr);
  k_attn<<<dim3(8, 64), 256, 0, stream>>>(qg, kg, vg, ctx);
  k_gemm8<8, 1><<<256, 512, 0, stream>>>(ctx, wot, nullptr, nullptr, nullptr, bo, out);
}

// Round 6
// 237.741 us; speedup vs baseline: 1.3339x; 1.3339x over previous
//
#include <hip/hip_runtime.h>
#include <hip/hip_bf16.h>
#include <math.h>

typedef __attribute__((ext_vector_type(4))) float f32x4;
typedef __attribute__((ext_vector_type(16))) float f32x16;
typedef __attribute__((ext_vector_type(8))) short bf16x8;
typedef __attribute__((ext_vector_type(4))) unsigned int u32x4;

#define DEV __device__ __forceinline__
#define MFMA16 __builtin_amdgcn_mfma_f32_16x16x32_bf16
#define MFMA32 __builtin_amdgcn_mfma_f32_32x32x16_bf16
#define SBAR __builtin_amdgcn_s_barrier()
#define SCHED0 __builtin_amdgcn_sched_barrier(0)

constexpr int S      = 2048;
constexpr int DMODEL = 1024;
constexpr int HD     = 64;
constexpr int MROWS  = 4 * 2048;   // B*S = 8192

DEV unsigned short f2bf(float f) {
  union { float f; unsigned int u; } v; v.f = f;
  unsigned int u = v.u;
  unsigned int r = u + 0x7fffu + ((u >> 16) & 1u);
  return (unsigned short)(r >> 16);
}

DEV unsigned int pkbf(float lo, float hi) {
  __hip_bfloat162 h = __float22bfloat162_rn(float2{lo, hi});
  union { __hip_bfloat162 h; unsigned int u; } c; c.h = h;
  return c.u;
}

DEV void gload_lds16(const void* g, void* l) {
  __builtin_amdgcn_global_load_lds(
      (const __attribute__((address_space(1))) unsigned int*)g,
      (__attribute__((address_space(3))) unsigned int*)l, 16, 0, 0);
}

// ---------------- fp32 -> bf16 convert (x) ----------------
__global__ __launch_bounds__(256) void k_conv(const float* __restrict__ in,
                                              unsigned short* __restrict__ out) {
  int i = blockIdx.x * 256 + threadIdx.x;
  float4 v = ((const float4*)in)[i];
  ushort4 o;
  o.x = f2bf(v.x); o.y = f2bf(v.y); o.z = f2bf(v.z); o.w = f2bf(v.w);
  ((ushort4*)out)[i] = o;
}

// ---------------- transpose + convert weights: Wt[n][k] = W[k][n] ----------------
__global__ __launch_bounds__(256) void k_transpose(const float* __restrict__ W,
                                                   unsigned short* __restrict__ Wt) {
  __shared__ float tile[32][33];
  int n0 = blockIdx.x * 32, k0 = blockIdx.y * 32;
  int tx = threadIdx.x, ty = threadIdx.y;  // (32,8)
#pragma unroll
  for (int j = 0; j < 4; ++j)
    tile[ty + j * 8][tx] = W[(size_t)(k0 + ty + j * 8) * DMODEL + n0 + tx];
  __syncthreads();
#pragma unroll
  for (int j = 0; j < 4; ++j)
    Wt[(size_t)(n0 + ty + j * 8) * DMODEL + k0 + tx] = f2bf(tile[tx][ty + j * 8]);
}

// ---------------- counted-vmcnt double-buffered GEMM (T3+T4+T5+T2) ----------------
// BM=256, BN=128, BK=64, 512 thr = 8 waves (4M x 2N), per-wave 64x64 output.
// EPI=0: scatter bf16 to Q/K/V (B,H,S,HD); Q pre-scaled by 0.125/ln2 (exp2 trick).
// EPI=1: fp32 out = acc + bo[n].
template<int NBX, int EPI>
__global__ __launch_bounds__(512, 2) void k_gemm8(const unsigned short* __restrict__ A,
                                                  const unsigned short* __restrict__ Bt,
                                                  unsigned short* __restrict__ Qg,
                                                  unsigned short* __restrict__ Kg,
                                                  unsigned short* __restrict__ Vg,
                                                  const float* __restrict__ bo,
                                                  float* __restrict__ out) {
  __shared__ __align__(16) char lds[98304];
  const int tid = threadIdx.x, lane = tid & 63;
  const int wid = tid >> 6, wm = wid >> 1, wn = wid & 1;
  const int lq = lane & 15, lg = lane >> 4;
  const int flat = blockIdx.x;
  const int wg = (flat & 7) * (NBX * 4) + (flat >> 3);
  const int by = wg / NBX, bx = wg % NBX;
  const int m0 = by * 256, n0 = bx * 128;

  auto stage = [&](int kt, int buf) {
    char* dA = lds + buf * 49152;
    char* dB = dA + 32768;
    const unsigned short* gA = A + (size_t)m0 * DMODEL + kt * 64;
    const unsigned short* gB = Bt + (size_t)n0 * DMODEL + kt * 64;
#pragma unroll
    for (int i = 0; i < 4; ++i) {
      int c = tid + i * 512; int r = c >> 3, cc = c & 7;
      gload_lds16(gA + (size_t)r * DMODEL + ((cc ^ (r & 7)) << 3), dA + c * 16);
    }
#pragma unroll
    for (int i = 0; i < 2; ++i) {
      int c = tid + i * 512; int r = c >> 3, cc = c & 7;
      gload_lds16(gB + (size_t)r * DMODEL + ((cc ^ (r & 7)) << 3), dB + c * 16);
    }
  };

  stage(0, 0);
  stage(1, 1);
  SCHED0;
  asm volatile("s_waitcnt vmcnt(6)" ::: "memory");
  SCHED0;
  SBAR;
  SCHED0;

  f32x4 acc[4][4] = {};
#pragma unroll 1
  for (int t = 0; t < 16; ++t) {
    const int cur = t & 1;
    const char* pA = lds + cur * 49152;
    const char* pB = pA + 32768;
    bf16x8 af[4][2], bf[4][2];
#pragma unroll
    for (int kk = 0; kk < 2; ++kk) {
#pragma unroll
      for (int mi = 0; mi < 4; ++mi) {
        int row = wm * 64 + mi * 16 + lq;
        af[mi][kk] = *(const bf16x8*)(pA + row * 128 + ((((kk << 2) + lg) ^ (row & 7)) << 4));
      }
#pragma unroll
      for (int ni = 0; ni < 4; ++ni) {
        int row = wn * 64 + ni * 16 + lq;
        bf[ni][kk] = *(const bf16x8*)(pB + row * 128 + ((((kk << 2) + lg) ^ (row & 7)) << 4));
      }
    }
    asm volatile("s_waitcnt lgkmcnt(0)" ::: "memory");
    SCHED0;
    SBAR;
    SCHED0;
    if (t < 14) stage(t + 2, cur);
    __builtin_amdgcn_s_setprio(1);
#pragma unroll
    for (int kk = 0; kk < 2; ++kk)
#pragma unroll
      for (int mi = 0; mi < 4; ++mi)
#pragma unroll
        for (int ni = 0; ni < 4; ++ni)
          acc[mi][ni] = MFMA16(af[mi][kk], bf[ni][kk], acc[mi][ni], 0, 0, 0);
    __builtin_amdgcn_s_setprio(0);
    SCHED0;
    if (t < 14) {
      asm volatile("s_waitcnt vmcnt(6)" ::: "memory");
    } else if (t == 14) {
      asm volatile("s_waitcnt vmcnt(0)" ::: "memory");
    }
    SCHED0;
    SBAR;
    SCHED0;
  }

  if (EPI == 0) {
#pragma unroll
    for (int mi = 0; mi < 4; ++mi)
#pragma unroll
      for (int ni = 0; ni < 4; ++ni) {
        int n = n0 + wn * 64 + ni * 16 + lq;
        int widx = n >> 10, nn = n & 1023;
        int h = nn >> 6, d = nn & 63;
        unsigned short* dst = (widx == 0) ? Qg : ((widx == 1) ? Kg : Vg);
        float scale = (widx == 0) ? 0.18033688f : 1.0f;
#pragma unroll
        for (int r = 0; r < 4; ++r) {
          int m = m0 + wm * 64 + mi * 16 + lg * 4 + r;
          int b_ = m >> 11, s_ = m & 2047;
          dst[(size_t)((b_ * 16 + h) * 2048 + s_) * HD + d] = f2bf(acc[mi][ni][r] * scale);
        }
      }
  } else {
#pragma unroll
    for (int mi = 0; mi < 4; ++mi)
#pragma unroll
      for (int ni = 0; ni < 4; ++ni) {
        int n = n0 + wn * 64 + ni * 16 + lq;
        float bv = bo[n];
#pragma unroll
        for (int r = 0; r < 4; ++r) {
          int m = m0 + wm * 64 + mi * 16 + lg * 4 + r;
          out[(size_t)m * DMODEL + n] = acc[mi][ni][r] + bv;
        }
      }
  }
}

// ---------------- causal flash attention: swapped-QK^T, in-register softmax ----------------
// 16 waves x 32 q-rows = 512-row blocks; grid (4,64) = 256 blocks = 1/CU,
// 16 waves/CU (4/SIMD). One shared K/V stream per block (threads<512 stage K via
// gload_lds; threads>=512 reg-stage V^T, T14 early-load/late-write).
// Scores in log2 units (Q pre-scaled 0.125/ln2).
__global__ __launch_bounds__(1024, 4) void k_attn(const unsigned short* __restrict__ Qg,
                                                  const unsigned short* __restrict__ Kg,
                                                  const unsigned short* __restrict__ Vg,
                                                  unsigned short* __restrict__ Ctx) {
  // main loop: [0,8K)x2 = sK dbuf, [16K,24K)x2 = sVT dbuf; epilogue: 16 x 4KB slices
  __shared__ __align__(16) char lds[65536];
  const int Qb = blockIdx.x;          // 0..3 (512 q-rows)
  const int bh = blockIdx.y;
  const int tid = threadIdx.x;
  const int lane = tid & 63, w = tid >> 6;   // w in 0..15
  const int lq5 = lane & 31, hi = lane >> 5;
  const size_t base = (size_t)bh * (S * HD);
  const int b = bh >> 4, h = bh & 15;

  const bool isV = (tid >= 512);
  const int c = tid & 511;
  const int krow = c >> 3, cc = c & 7;       // tile-local row + 16B chunk
  const int scc = cc ^ (krow & 7);           // pre-swizzled K source chunk

  const int q0w = Qb * 512 + w * 32;
  const int tmax = 8 * Qb + 7;
  const int diag = q0w >> 6;

  bf16x8 qF[4];
#pragma unroll
  for (int dc = 0; dc < 4; ++dc)
    qF[dc] = *(const bf16x8*)(Qg + base + (size_t)(q0w + lq5) * HD + dc * 16 + hi * 8);

  f32x16 o0 = {}, o1 = {};
  float m_run = -INFINITY, l_run = 0.f;

  // prologue: stage tile 0
  if (!isV) {
    gload_lds16(Kg + base + (size_t)krow * HD + scc * 8, lds + c * 16);
  } else {
    bf16x8 vv = *(const bf16x8*)(Vg + base + (size_t)krow * HD + cc * 8);
#pragma unroll
    for (int j = 0; j < 8; ++j) {
      int d = cc * 8 + j;
      int fd = (d & 7) ^ ((d >> 3) & 7);
      *(unsigned short*)(lds + 16384 + d * 128 + (((krow >> 3) ^ fd) << 4) + (krow & 7) * 2) =
          (unsigned short)vv[j];
    }
  }
  __syncthreads();

#pragma unroll 1
  for (int t = 0; t <= tmax; ++t) {
    const int cur = t & 1, nxt = cur ^ 1;
    char* sK  = lds + cur * 8192;
    char* sVT = lds + 16384 + cur * 8192;
    const bool have_next = (t < tmax);
    bf16x8 vv;
    if (have_next) {   // T14: issue next-tile loads EARLY
      if (!isV)
        gload_lds16(Kg + base + (size_t)((t + 1) * 64 + krow) * HD + scc * 8,
                    lds + nxt * 8192 + c * 16);
      else
        vv = *(const bf16x8*)(Vg + base + (size_t)((t + 1) * 64 + krow) * HD + cc * 8);
    }
    const bool active = (t <= diag);
    if (active) {
      const bool isdiag = (t == diag);
      const int nkb = (isdiag && !(q0w & 32)) ? 1 : 2;
      f32x16 st0 = {}, st1 = {};
      __builtin_amdgcn_s_setprio(1);
#pragma unroll
      for (int dc = 0; dc < 4; ++dc) {
        int row = lq5;
        bf16x8 a0 = *(const bf16x8*)(sK + row * 128 + (((2 * dc + hi) ^ (row & 7)) << 4));
        st0 = MFMA32(a0, qF[dc], st0, 0, 0, 0);
      }
      if (nkb == 2) {
#pragma unroll
        for (int dc = 0; dc < 4; ++dc) {
          int row = 32 + lq5;
          bf16x8 a1 = *(const bf16x8*)(sK + row * 128 + (((2 * dc + hi) ^ (row & 7)) << 4));
          st1 = MFMA32(a1, qF[dc], st1, 0, 0, 0);
        }
      }
      __builtin_amdgcn_s_setprio(0);
      if (isdiag) {
        int qo = q0w + lq5 - t * 64;
        if (q0w & 32) {
#pragma unroll
          for (int r = 0; r < 16; ++r) {
            int key = 32 + (r & 3) + 8 * (r >> 2) + 4 * hi;
            st1[r] = (key > qo) ? -INFINITY : st1[r];
          }
        } else {
#pragma unroll
          for (int r = 0; r < 16; ++r) {
            int key = (r & 3) + 8 * (r >> 2) + 4 * hi;
            st0[r] = (key > qo) ? -INFINITY : st0[r];
          }
        }
      }
      float mx = st0[0];
#pragma unroll
      for (int r = 1; r < 16; ++r) mx = fmaxf(mx, st0[r]);
      if (nkb == 2) {
#pragma unroll
        for (int r = 0; r < 16; ++r) mx = fmaxf(mx, st1[r]);
      }
      mx = fmaxf(mx, __shfl_xor(mx, 32));
      bool need = !(mx <= m_run + 8.0f);
      if (__any(need)) {
        float mn = fmaxf(m_run, mx);
        float alpha = exp2f(m_run - mn);
        m_run = mn;
        l_run *= alpha;
#pragma unroll
        for (int r = 0; r < 16; ++r) { o0[r] *= alpha; o1[r] *= alpha; }
      }
      float rs[4] = {0.f, 0.f, 0.f, 0.f};
#pragma unroll
      for (int r = 0; r < 16; ++r) {
        float p = exp2f(st0[r] - m_run);
        st0[r] = p;
        rs[r & 3] += p;
      }
      if (nkb == 2) {
#pragma unroll
        for (int r = 0; r < 16; ++r) {
          float p = exp2f(st1[r] - m_run);
          st1[r] = p;
          rs[r & 3] += p;
        }
      }
      float rsum = (rs[0] + rs[1]) + (rs[2] + rs[3]);
      rsum += __shfl_xor(rsum, 32);
      l_run += rsum;
      {
        unsigned int wv[8];
#pragma unroll
        for (int j = 0; j < 8; ++j) wv[j] = pkbf(st0[2 * j], st0[2 * j + 1]);
        asm("v_permlane32_swap_b32 %0, %1" : "+v"(wv[0]), "+v"(wv[2]));
        asm("v_permlane32_swap_b32 %0, %1" : "+v"(wv[1]), "+v"(wv[3]));
        asm("v_permlane32_swap_b32 %0, %1" : "+v"(wv[4]), "+v"(wv[6]));
        asm("v_permlane32_swap_b32 %0, %1" : "+v"(wv[5]), "+v"(wv[7]));
        union { bf16x8 v; unsigned int u[4]; } fa, fb;
        fa.u[0] = wv[0]; fa.u[1] = wv[1]; fa.u[2] = wv[2]; fa.u[3] = wv[3];
        fb.u[0] = wv[4]; fb.u[1] = wv[5]; fb.u[2] = wv[6]; fb.u[3] = wv[7];
        __builtin_amdgcn_s_setprio(1);
#pragma unroll
        for (int kc = 0; kc < 2; ++kc) {
          bf16x8 bp = kc ? fb.v : fa.v;
          {
            int d = lq5, fd = (d & 7) ^ ((d >> 3) & 7);
            bf16x8 av = *(const bf16x8*)(sVT + d * 128 + (((kc * 2 + hi) ^ fd) << 4));
            o0 = MFMA32(av, bp, o0, 0, 0, 0);
          }
          {
            int d = 32 + lq5, fd = (d & 7) ^ ((d >> 3) & 7);
            bf16x8 av = *(const bf16x8*)(sVT + d * 128 + (((kc * 2 + hi) ^ fd) << 4));
            o1 = MFMA32(av, bp, o1, 0, 0, 0);
          }
        }
        __builtin_amdgcn_s_setprio(0);
      }
      if (nkb == 2) {
        unsigned int wv[8];
#pragma unroll
        for (int j = 0; j < 8; ++j) wv[j] = pkbf(st1[2 * j], st1[2 * j + 1]);
        asm("v_permlane32_swap_b32 %0, %1" : "+v"(wv[0]), "+v"(wv[2]));
        asm("v_permlane32_swap_b32 %0, %1" : "+v"(wv[1]), "+v"(wv[3]));
        asm("v_permlane32_swap_b32 %0, %1" : "+v"(wv[4]), "+v"(wv[6]));
        asm("v_permlane32_swap_b32 %0, %1" : "+v"(wv[5]), "+v"(wv[7]));
        union { bf16x8 v; unsigned int u[4]; } fa, fb;
        fa.u[0] = wv[0]; fa.u[1] = wv[1]; fa.u[2] = wv[2]; fa.u[3] = wv[3];
        fb.u[0] = wv[4]; fb.u[1] = wv[5]; fb.u[2] = wv[6]; fb.u[3] = wv[7];
        __builtin_amdgcn_s_setprio(1);
#pragma unroll
        for (int kc = 0; kc < 2; ++kc) {
          bf16x8 bp = kc ? fb.v : fa.v;
          {
            int d = lq5, fd = (d & 7) ^ ((d >> 3) & 7);
            bf16x8 av = *(const bf16x8*)(sVT + d * 128 + ((((2 + kc) * 2 + hi) ^ fd) << 4));
            o0 = MFMA32(av, bp, o0, 0, 0, 0);
          }
          {
            int d = 32 + lq5, fd = (d & 7) ^ ((d >> 3) & 7);
            bf16x8 av = *(const bf16x8*)(sVT + d * 128 + ((((2 + kc) * 2 + hi) ^ fd) << 4));
            o1 = MFMA32(av, bp, o1, 0, 0, 0);
          }
        }
        __builtin_amdgcn_s_setprio(0);
      }
    }
    if (have_next && isV) {   // T14: write staged V LATE
      char* dVT = lds + 16384 + nxt * 8192;
#pragma unroll
      for (int j = 0; j < 8; ++j) {
        int d = cc * 8 + j;
        int fd = (d & 7) ^ ((d >> 3) & 7);
        *(unsigned short*)(dVT + d * 128 + (((krow >> 3) ^ fd) << 4) + (krow & 7) * 2) =
            (unsigned short)vv[j];
      }
    }
    __syncthreads();
  }

  // epilogue: normalize, stage via per-wave LDS slice for coalesced stores
  __syncthreads();
  {
    float inv = 1.0f / l_run;
    char* slice = lds + w * 4096;   // 16 waves x 4KB = 64KB
#pragma unroll
    for (int db = 0; db < 2; ++db)
#pragma unroll
      for (int j = 0; j < 8; ++j) {
        int d0 = (j & 1) * 2 + (j >> 1) * 8 + 4 * hi + 32 * db;
        float va = (db ? o1[2 * j] : o0[2 * j]) * inv;
        float vb = (db ? o1[2 * j + 1] : o0[2 * j + 1]) * inv;
        *(unsigned int*)(slice + lq5 * 128 + (((d0 >> 3) ^ (lq5 & 7)) << 4) + (d0 & 7) * 2) =
            pkbf(va, vb);
      }
    asm volatile("s_waitcnt lgkmcnt(0)" ::: "memory");
#pragma unroll
    for (int i = 0; i < 4; ++i) {
      int r = lane >> 1, cc2 = (lane & 1) * 4 + i;
      u32x4 v = *(const u32x4*)(slice + r * 128 + ((cc2 ^ (r & 7)) << 4));
      *(u32x4*)(Ctx + (size_t)(b * S + q0w + r) * DMODEL + h * HD + cc2 * 8) = v;
    }
  }
}

extern "C" void kernel_launch(void* const* d_in, const int* in_sizes, int n_in,
                              void* d_out, int out_size, void* d_ws, size_t ws_size,
                              hipStream_t stream) {
  const float* x  = (const float*)d_in[0];
  const float* Wq = (const float*)d_in[1];
  const float* Wk = (const float*)d_in[2];
  const float* Wv = (const float*)d_in[3];
  const float* Wo = (const float*)d_in[4];
  const float* bo = (const float*)d_in[5];
  float* out = (float*)d_out;

  char* p = (char*)d_ws;
  unsigned short* xb  = (unsigned short*)p; p += (size_t)MROWS * DMODEL * 2;
  unsigned short* wt  = (unsigned short*)p; p += (size_t)3 * DMODEL * DMODEL * 2;
  unsigned short* wot = (unsigned short*)p; p += (size_t)DMODEL * DMODEL * 2;
  unsigned short* qg  = (unsigned short*)p; p += (size_t)MROWS * DMODEL * 2;
  unsigned short* kg  = (unsigned short*)p; p += (size_t)MROWS * DMODEL * 2;
  unsigned short* vg  = (unsigned short*)p; p += (size_t)MROWS * DMODEL * 2;
  unsigned short* ctx = (unsigned short*)p; p += (size_t)MROWS * DMODEL * 2;

  k_conv<<<(MROWS * DMODEL) / 1024, 256, 0, stream>>>(x, xb);
  dim3 tb(32, 8), tg(32, 32);
  k_transpose<<<tg, tb, 0, stream>>>(Wq, wt);
  k_transpose<<<tg, tb, 0, stream>>>(Wk, wt + (size_t)DMODEL * DMODEL);
  k_transpose<<<tg, tb, 0, stream>>>(Wv, wt + (size_t)2 * DMODEL * DMODEL);
  k_transpose<<<tg, tb, 0, stream>>>(Wo, wot);
  k_gemm8<24, 0><<<768, 512, 0, stream>>>(xb, wt, qg, kg, vg, nullptr, nullptr);
  k_attn<<<dim3(4, 64), 1024, 0, stream>>>(qg, kg, vg, ctx);
  k_gemm8<8, 1><<<256, 512, 0, stream>>>(ctx, wot, nullptr, nullptr, nullptr, bo, out);
}

// Round 7
// 201.585 us; speedup vs baseline: 1.5731x; 1.1794x over previous
//
#include <hip/hip_runtime.h>
#include <hip/hip_bf16.h>
#include <math.h>

typedef __attribute__((ext_vector_type(4))) float f32x4;
typedef __attribute__((ext_vector_type(16))) float f32x16;
typedef __attribute__((ext_vector_type(8))) short bf16x8;
typedef __attribute__((ext_vector_type(4))) unsigned int u32x4;

#define DEV __device__ __forceinline__
#define MFMA16 __builtin_amdgcn_mfma_f32_16x16x32_bf16
#define MFMA32 __builtin_amdgcn_mfma_f32_32x32x16_bf16
#define SBAR __builtin_amdgcn_s_barrier()
#define SCHED0 __builtin_amdgcn_sched_barrier(0)

constexpr int S      = 2048;
constexpr int DMODEL = 1024;
constexpr int HD     = 64;
constexpr int MROWS  = 4 * 2048;   // B*S = 8192

DEV unsigned short f2bf(float f) {
  union { float f; unsigned int u; } v; v.f = f;
  unsigned int u = v.u;
  unsigned int r = u + 0x7fffu + ((u >> 16) & 1u);
  return (unsigned short)(r >> 16);
}

DEV unsigned int pkbf(float lo, float hi) {
  __hip_bfloat162 h = __float22bfloat162_rn(float2{lo, hi});
  union { __hip_bfloat162 h; unsigned int u; } c; c.h = h;
  return c.u;
}

DEV void gload_lds16(const void* g, void* l) {
  __builtin_amdgcn_global_load_lds(
      (const __attribute__((address_space(1))) unsigned int*)g,
      (__attribute__((address_space(3))) unsigned int*)l, 16, 0, 0);
}

// ---------------- fp32 -> bf16 convert (x) ----------------
__global__ __launch_bounds__(256) void k_conv(const float* __restrict__ in,
                                              unsigned short* __restrict__ out) {
  int i = blockIdx.x * 256 + threadIdx.x;
  float4 v = ((const float4*)in)[i];
  ushort4 o;
  o.x = f2bf(v.x); o.y = f2bf(v.y); o.z = f2bf(v.z); o.w = f2bf(v.w);
  ((ushort4*)out)[i] = o;
}

// ---------------- transpose + convert all 4 weights (merged launch) ----------------
// z in 0..3 selects Wq/Wk/Wv/Wo; Wt layout: wt[z][n][k] = W[k][n] (wot for z==3).
__global__ __launch_bounds__(256) void k_transpose4(const float* __restrict__ Wq,
                                                    const float* __restrict__ Wk,
                                                    const float* __restrict__ Wv,
                                                    const float* __restrict__ Wo,
                                                    unsigned short* __restrict__ wt,
                                                    unsigned short* __restrict__ wot) {
  __shared__ float tile[32][33];
  const int z = blockIdx.z;
  const float* W = (z == 0) ? Wq : (z == 1) ? Wk : (z == 2) ? Wv : Wo;
  unsigned short* Wt = (z == 3) ? wot : wt + (size_t)z * DMODEL * DMODEL;
  int n0 = blockIdx.x * 32, k0 = blockIdx.y * 32;
  int tx = threadIdx.x, ty = threadIdx.y;  // (32,8)
#pragma unroll
  for (int j = 0; j < 4; ++j)
    tile[ty + j * 8][tx] = W[(size_t)(k0 + ty + j * 8) * DMODEL + n0 + tx];
  __syncthreads();
#pragma unroll
  for (int j = 0; j < 4; ++j)
    Wt[(size_t)(n0 + ty + j * 8) * DMODEL + k0 + tx] = f2bf(tile[tx][ty + j * 8]);
}

// ---------------- counted-vmcnt double-buffered GEMM (T3+T4+T5+T2) ----------------
// BM=256, BN=128, BK=64, 512 thr = 8 waves (4M x 2N), per-wave 64x64 output.
// EPI=0: scatter bf16 to Q/K/V (B,H,S,HD); Q pre-scaled by 0.125/ln2 (exp2 trick).
// EPI=1: fp32 out = acc + bo[n].
template<int NBX, int EPI>
__global__ __launch_bounds__(512, 2) void k_gemm8(const unsigned short* __restrict__ A,
                                                  const unsigned short* __restrict__ Bt,
                                                  unsigned short* __restrict__ Qg,
                                                  unsigned short* __restrict__ Kg,
                                                  unsigned short* __restrict__ Vg,
                                                  const float* __restrict__ bo,
                                                  float* __restrict__ out) {
  __shared__ __align__(16) char lds[98304];
  const int tid = threadIdx.x, lane = tid & 63;
  const int wid = tid >> 6, wm = wid >> 1, wn = wid & 1;
  const int lq = lane & 15, lg = lane >> 4;
  const int flat = blockIdx.x;
  const int wg = (flat & 7) * (NBX * 4) + (flat >> 3);
  const int by = wg / NBX, bx = wg % NBX;
  const int m0 = by * 256, n0 = bx * 128;

  auto stage = [&](int kt, int buf) {
    char* dA = lds + buf * 49152;
    char* dB = dA + 32768;
    const unsigned short* gA = A + (size_t)m0 * DMODEL + kt * 64;
    const unsigned short* gB = Bt + (size_t)n0 * DMODEL + kt * 64;
#pragma unroll
    for (int i = 0; i < 4; ++i) {
      int c = tid + i * 512; int r = c >> 3, cc = c & 7;
      gload_lds16(gA + (size_t)r * DMODEL + ((cc ^ (r & 7)) << 3), dA + c * 16);
    }
#pragma unroll
    for (int i = 0; i < 2; ++i) {
      int c = tid + i * 512; int r = c >> 3, cc = c & 7;
      gload_lds16(gB + (size_t)r * DMODEL + ((cc ^ (r & 7)) << 3), dB + c * 16);
    }
  };

  stage(0, 0);
  stage(1, 1);
  SCHED0;
  asm volatile("s_waitcnt vmcnt(6)" ::: "memory");
  SCHED0;
  SBAR;
  SCHED0;

  f32x4 acc[4][4] = {};
#pragma unroll 1
  for (int t = 0; t < 16; ++t) {
    const int cur = t & 1;
    const char* pA = lds + cur * 49152;
    const char* pB = pA + 32768;
    bf16x8 af[4][2], bf[4][2];
#pragma unroll
    for (int kk = 0; kk < 2; ++kk) {
#pragma unroll
      for (int mi = 0; mi < 4; ++mi) {
        int row = wm * 64 + mi * 16 + lq;
        af[mi][kk] = *(const bf16x8*)(pA + row * 128 + ((((kk << 2) + lg) ^ (row & 7)) << 4));
      }
#pragma unroll
      for (int ni = 0; ni < 4; ++ni) {
        int row = wn * 64 + ni * 16 + lq;
        bf[ni][kk] = *(const bf16x8*)(pB + row * 128 + ((((kk << 2) + lg) ^ (row & 7)) << 4));
      }
    }
    asm volatile("s_waitcnt lgkmcnt(0)" ::: "memory");
    SCHED0;
    SBAR;
    SCHED0;
    if (t < 14) stage(t + 2, cur);
    __builtin_amdgcn_s_setprio(1);
#pragma unroll
    for (int kk = 0; kk < 2; ++kk)
#pragma unroll
      for (int mi = 0; mi < 4; ++mi)
#pragma unroll
        for (int ni = 0; ni < 4; ++ni)
          acc[mi][ni] = MFMA16(af[mi][kk], bf[ni][kk], acc[mi][ni], 0, 0, 0);
    __builtin_amdgcn_s_setprio(0);
    SCHED0;
    if (t < 14) {
      asm volatile("s_waitcnt vmcnt(6)" ::: "memory");
    } else if (t == 14) {
      asm volatile("s_waitcnt vmcnt(0)" ::: "memory");
    }
    SCHED0;
    SBAR;
    SCHED0;
  }

  if (EPI == 0) {
#pragma unroll
    for (int mi = 0; mi < 4; ++mi)
#pragma unroll
      for (int ni = 0; ni < 4; ++ni) {
        int n = n0 + wn * 64 + ni * 16 + lq;
        int widx = n >> 10, nn = n & 1023;
        int h = nn >> 6, d = nn & 63;
        unsigned short* dst = (widx == 0) ? Qg : ((widx == 1) ? Kg : Vg);
        float scale = (widx == 0) ? 0.18033688f : 1.0f;
#pragma unroll
        for (int r = 0; r < 4; ++r) {
          int m = m0 + wm * 64 + mi * 16 + lg * 4 + r;
          int b_ = m >> 11, s_ = m & 2047;
          dst[(size_t)((b_ * 16 + h) * 2048 + s_) * HD + d] = f2bf(acc[mi][ni][r] * scale);
        }
      }
  } else {
#pragma unroll
    for (int mi = 0; mi < 4; ++mi)
#pragma unroll
      for (int ni = 0; ni < 4; ++ni) {
        int n = n0 + wn * 64 + ni * 16 + lq;
        float bv = bo[n];
#pragma unroll
        for (int r = 0; r < 4; ++r) {
          int m = m0 + wm * 64 + mi * 16 + lg * 4 + r;
          out[(size_t)m * DMODEL + n] = acc[mi][ni][r] + bv;
        }
      }
  }
}

// ---------------- causal flash attention: swapped-QK^T, in-register softmax ----------------
// ROUND-3 PROVEN STRUCTURE (82.8us): 8 waves x 32 q-rows = 256-row blocks;
// pairs (p, 7-p) -> uniform 36 tile-iters; grid (4,64) = 256 blocks = 1/CU.
// Deltas vs round 3: exp2-domain softmax (Q pre-scaled 0.125/ln2) + setprio on MFMA.
__global__ __launch_bounds__(512, 2) void k_attn(const unsigned short* __restrict__ Qg,
                                                 const unsigned short* __restrict__ Kg,
                                                 const unsigned short* __restrict__ Vg,
                                                 unsigned short* __restrict__ Ctx) {
  // [0,8K): sK buf0  [8K,16K): sK buf1  [16K,24K): sVT buf0  [24K,32K): sVT buf1
  __shared__ __align__(16) char lds[32768];
  const int pr = blockIdx.x;          // 0..3
  const int bh = blockIdx.y;
  const int tid = threadIdx.x;
  const int lane = tid & 63, w = tid >> 6;
  const int lq5 = lane & 31, hi = lane >> 5;
  const size_t base = (size_t)bh * (S * HD);
  const int b = bh >> 4, h = bh & 15;
  const int vkrow = tid >> 3, vcc = tid & 7;   // V staging: chunk tid = V[krow][cc*8..+7]

#pragma unroll 1
  for (int half = 0; half < 2; ++half) {
    const int Qb = half ? (7 - pr) : pr;
    const int q0w = Qb * 256 + w * 32;
    const int tmax = 4 * Qb + 3;
    const int diag = q0w >> 6;

    bf16x8 qF[4];
#pragma unroll
    for (int dc = 0; dc < 4; ++dc)
      qF[dc] = *(const bf16x8*)(Qg + base + (size_t)(q0w + lq5) * HD + dc * 16 + hi * 8);

    f32x16 o0 = {}, o1 = {};
    float m_run = -INFINITY, l_run = 0.f;

    __syncthreads();   // protect LDS from previous half's epilogue reads
    // prologue: stage tile 0 into buf0
    {
      int row = tid >> 3, cc = tid & 7, scc = cc ^ (row & 7);
      gload_lds16(Kg + base + (size_t)row * HD + scc * 8, lds + tid * 16);
      bf16x8 vv = *(const bf16x8*)(Vg + base + (size_t)vkrow * HD + vcc * 8);
#pragma unroll
      for (int j = 0; j < 8; ++j) {
        int d = vcc * 8 + j;
        int fd = (d & 7) ^ ((d >> 3) & 7);
        *(unsigned short*)(lds + 16384 + d * 128 + (((vkrow >> 3) ^ fd) << 4) + (vkrow & 7) * 2) =
            (unsigned short)vv[j];
      }
    }
    __syncthreads();

#pragma unroll 1
    for (int t = 0; t <= tmax; ++t) {
      const int cur = t & 1, nxt = cur ^ 1;
      char* sK  = lds + cur * 8192;
      char* sVT = lds + 16384 + cur * 8192;
      const bool have_next = (t < tmax);
      bf16x8 vv;
      if (have_next) {   // T14: issue next-tile loads EARLY
        vv = *(const bf16x8*)(Vg + base + (size_t)((t + 1) * 64 + vkrow) * HD + vcc * 8);
        int row = tid >> 3, cc = tid & 7, scc = cc ^ (row & 7);
        gload_lds16(Kg + base + (size_t)((t + 1) * 64 + row) * HD + scc * 8,
                    lds + nxt * 8192 + tid * 16);
      }
      const bool active = (t <= diag);
      if (active) {
        const bool isdiag = (t == diag);
        const int nkb = (isdiag && !(q0w & 32)) ? 1 : 2;
        // ---- QK^T swapped: st[k][q], scores in log2 units ----
        f32x16 st0 = {}, st1 = {};
        __builtin_amdgcn_s_setprio(1);
#pragma unroll
        for (int dc = 0; dc < 4; ++dc) {
          int row = lq5;
          bf16x8 a0 = *(const bf16x8*)(sK + row * 128 + (((2 * dc + hi) ^ (row & 7)) << 4));
          st0 = MFMA32(a0, qF[dc], st0, 0, 0, 0);
        }
        if (nkb == 2) {
#pragma unroll
          for (int dc = 0; dc < 4; ++dc) {
            int row = 32 + lq5;
            bf16x8 a1 = *(const bf16x8*)(sK + row * 128 + (((2 * dc + hi) ^ (row & 7)) << 4));
            st1 = MFMA32(a1, qF[dc], st1, 0, 0, 0);
          }
        }
        __builtin_amdgcn_s_setprio(0);
        // ---- mask (diagonal tile only) ----
        if (isdiag) {
          int qo = q0w + lq5 - t * 64;
          if (q0w & 32) {
#pragma unroll
            for (int r = 0; r < 16; ++r) {
              int key = 32 + (r & 3) + 8 * (r >> 2) + 4 * hi;
              st1[r] = (key > qo) ? -INFINITY : st1[r];
            }
          } else {
#pragma unroll
            for (int r = 0; r < 16; ++r) {
              int key = (r & 3) + 8 * (r >> 2) + 4 * hi;
              st0[r] = (key > qo) ? -INFINITY : st0[r];
            }
          }
        }
        // ---- row max: in-lane tree + one cross-pair swap ----
        float mx = st0[0];
#pragma unroll
        for (int r = 1; r < 16; ++r) mx = fmaxf(mx, st0[r]);
        if (nkb == 2) {
#pragma unroll
          for (int r = 0; r < 16; ++r) mx = fmaxf(mx, st1[r]);
        }
        mx = fmaxf(mx, __shfl_xor(mx, 32));
        // ---- defer-max (T13, THR=8 in log2 units -> P <= 256) ----
        bool need = !(mx <= m_run + 8.0f);
        if (__any(need)) {
          float mn = fmaxf(m_run, mx);
          float alpha = exp2f(m_run - mn);
          m_run = mn;
          l_run *= alpha;
#pragma unroll
          for (int r = 0; r < 16; ++r) { o0[r] *= alpha; o1[r] *= alpha; }
        }
        // ---- exp2 + row sum ----
        float rs[4] = {0.f, 0.f, 0.f, 0.f};
#pragma unroll
        for (int r = 0; r < 16; ++r) {
          float p = exp2f(st0[r] - m_run);
          st0[r] = p;
          rs[r & 3] += p;
        }
        if (nkb == 2) {
#pragma unroll
          for (int r = 0; r < 16; ++r) {
            float p = exp2f(st1[r] - m_run);
            st1[r] = p;
            rs[r & 3] += p;
          }
        }
        float rsum = (rs[0] + rs[1]) + (rs[2] + rs[3]);
        rsum += __shfl_xor(rsum, 32);
        l_run += rsum;
        // ---- P -> bf16 B-frags via cvt_pk + permlane32_swap (T12); PV: O^T += V^T.P^T ----
        {
          unsigned int wv[8];
#pragma unroll
          for (int j = 0; j < 8; ++j) wv[j] = pkbf(st0[2 * j], st0[2 * j + 1]);
          asm("v_permlane32_swap_b32 %0, %1" : "+v"(wv[0]), "+v"(wv[2]));
          asm("v_permlane32_swap_b32 %0, %1" : "+v"(wv[1]), "+v"(wv[3]));
          asm("v_permlane32_swap_b32 %0, %1" : "+v"(wv[4]), "+v"(wv[6]));
          asm("v_permlane32_swap_b32 %0, %1" : "+v"(wv[5]), "+v"(wv[7]));
          union { bf16x8 v; unsigned int u[4]; } fa, fb;
          fa.u[0] = wv[0]; fa.u[1] = wv[1]; fa.u[2] = wv[2]; fa.u[3] = wv[3];
          fb.u[0] = wv[4]; fb.u[1] = wv[5]; fb.u[2] = wv[6]; fb.u[3] = wv[7];
          __builtin_amdgcn_s_setprio(1);
#pragma unroll
          for (int kc = 0; kc < 2; ++kc) {   // kc4 = kc (kb=0)
            bf16x8 bp = kc ? fb.v : fa.v;
            {
              int d = lq5, fd = (d & 7) ^ ((d >> 3) & 7);
              bf16x8 av = *(const bf16x8*)(sVT + d * 128 + (((kc * 2 + hi) ^ fd) << 4));
              o0 = MFMA32(av, bp, o0, 0, 0, 0);
            }
            {
              int d = 32 + lq5, fd = (d & 7) ^ ((d >> 3) & 7);
              bf16x8 av = *(const bf16x8*)(sVT + d * 128 + (((kc * 2 + hi) ^ fd) << 4));
              o1 = MFMA32(av, bp, o1, 0, 0, 0);
            }
          }
          __builtin_amdgcn_s_setprio(0);
        }
        if (nkb == 2) {
          unsigned int wv[8];
#pragma unroll
          for (int j = 0; j < 8; ++j) wv[j] = pkbf(st1[2 * j], st1[2 * j + 1]);
          asm("v_permlane32_swap_b32 %0, %1" : "+v"(wv[0]), "+v"(wv[2]));
          asm("v_permlane32_swap_b32 %0, %1" : "+v"(wv[1]), "+v"(wv[3]));
          asm("v_permlane32_swap_b32 %0, %1" : "+v"(wv[4]), "+v"(wv[6]));
          asm("v_permlane32_swap_b32 %0, %1" : "+v"(wv[5]), "+v"(wv[7]));
          union { bf16x8 v; unsigned int u[4]; } fa, fb;
          fa.u[0] = wv[0]; fa.u[1] = wv[1]; fa.u[2] = wv[2]; fa.u[3] = wv[3];
          fb.u[0] = wv[4]; fb.u[1] = wv[5]; fb.u[2] = wv[6]; fb.u[3] = wv[7];
          __builtin_amdgcn_s_setprio(1);
#pragma unroll
          for (int kc = 0; kc < 2; ++kc) {   // kc4 = 2 + kc (kb=1)
            bf16x8 bp = kc ? fb.v : fa.v;
            {
              int d = lq5, fd = (d & 7) ^ ((d >> 3) & 7);
              bf16x8 av = *(const bf16x8*)(sVT + d * 128 + ((((2 + kc) * 2 + hi) ^ fd) << 4));
              o0 = MFMA32(av, bp, o0, 0, 0, 0);
            }
            {
              int d = 32 + lq5, fd = (d & 7) ^ ((d >> 3) & 7);
              bf16x8 av = *(const bf16x8*)(sVT + d * 128 + ((((2 + kc) * 2 + hi) ^ fd) << 4));
              o1 = MFMA32(av, bp, o1, 0, 0, 0);
            }
          }
          __builtin_amdgcn_s_setprio(0);
        }
      }
      // T14: write staged V LATE (vv HBM latency hidden under QK/softmax/PV)
      if (have_next) {
        char* dVT = lds + 16384 + nxt * 8192;
#pragma unroll
        for (int j = 0; j < 8; ++j) {
          int d = vcc * 8 + j;
          int fd = (d & 7) ^ ((d >> 3) & 7);
          *(unsigned short*)(dVT + d * 128 + (((vkrow >> 3) ^ fd) << 4) + (vkrow & 7) * 2) =
              (unsigned short)vv[j];
        }
      }
      __syncthreads();
    }

    // ---- epilogue: normalize, stage via LDS slice for coalesced stores ----
    __syncthreads();
    {
      float inv = 1.0f / l_run;
      char* slice = lds + w * 4096;   // [32 q][64 d] bf16, chunk-swizzled rows
#pragma unroll
      for (int db = 0; db < 2; ++db)
#pragma unroll
        for (int j = 0; j < 8; ++j) {
          int d0 = (j & 1) * 2 + (j >> 1) * 8 + 4 * hi + 32 * db;
          float va = (db ? o1[2 * j] : o0[2 * j]) * inv;
          float vb = (db ? o1[2 * j + 1] : o0[2 * j + 1]) * inv;
          *(unsigned int*)(slice + lq5 * 128 + (((d0 >> 3) ^ (lq5 & 7)) << 4) + (d0 & 7) * 2) =
              pkbf(va, vb);
        }
      asm volatile("s_waitcnt lgkmcnt(0)" ::: "memory");
#pragma unroll
      for (int i = 0; i < 4; ++i) {
        int r = lane >> 1, cc = (lane & 1) * 4 + i;
        u32x4 v = *(const u32x4*)(slice + r * 128 + ((cc ^ (r & 7)) << 4));
        *(u32x4*)(Ctx + (size_t)(b * S + q0w + r) * DMODEL + h * HD + cc * 8) = v;
      }
    }
  }
}

extern "C" void kernel_launch(void* const* d_in, const int* in_sizes, int n_in,
                              void* d_out, int out_size, void* d_ws, size_t ws_size,
                              hipStream_t stream) {
  const float* x  = (const float*)d_in[0];
  const float* Wq = (const float*)d_in[1];
  const float* Wk = (const float*)d_in[2];
  const float* Wv = (const float*)d_in[3];
  const float* Wo = (const float*)d_in[4];
  const float* bo = (const float*)d_in[5];
  float* out = (float*)d_out;

  char* p = (char*)d_ws;
  unsigned short* xb  = (unsigned short*)p; p += (size_t)MROWS * DMODEL * 2;
  unsigned short* wt  = (unsigned short*)p; p += (size_t)3 * DMODEL * DMODEL * 2;
  unsigned short* wot = (unsigned short*)p; p += (size_t)DMODEL * DMODEL * 2;
  unsigned short* qg  = (unsigned short*)p; p += (size_t)MROWS * DMODEL * 2;
  unsigned short* kg  = (unsigned short*)p; p += (size_t)MROWS * DMODEL * 2;
  unsigned short* vg  = (unsigned short*)p; p += (size_t)MROWS * DMODEL * 2;
  unsigned short* ctx = (unsigned short*)p; p += (size_t)MROWS * DMODEL * 2;

  k_conv<<<(MROWS * DMODEL) / 1024, 256, 0, stream>>>(x, xb);
  k_transpose4<<<dim3(32, 32, 4), dim3(32, 8), 0, stream>>>(Wq, Wk, Wv, Wo, wt, wot);
  k_gemm8<24, 0><<<768, 512, 0, stream>>>(xb, wt, qg, kg, vg, nullptr, nullptr);
  k_attn<<<dim3(4, 64), 512, 0, stream>>>(qg, kg, vg, ctx);
  k_gemm8<8, 1><<<256, 512, 0, stream>>>(ctx, wot, nullptr, nullptr, nullptr, bo, out);
}

// Round 8
// 179.552 us; speedup vs baseline: 1.7662x; 1.1227x over previous
//
#include <hip/hip_runtime.h>
#include <hip/hip_bf16.h>
#include <math.h>

typedef __attribute__((ext_vector_type(4))) float f32x4;
typedef __attribute__((ext_vector_type(16))) float f32x16;
typedef __attribute__((ext_vector_type(8))) short bf16x8;
typedef __attribute__((ext_vector_type(4))) unsigned int u32x4;

#define DEV __device__ __forceinline__
#define MFMA16 __builtin_amdgcn_mfma_f32_16x16x32_bf16
#define MFMA32 __builtin_amdgcn_mfma_f32_32x32x16_bf16
#define SBAR __builtin_amdgcn_s_barrier()
#define SCHED0 __builtin_amdgcn_sched_barrier(0)

constexpr int S      = 2048;
constexpr int DMODEL = 1024;
constexpr int HD     = 64;
constexpr int MROWS  = 4 * 2048;   // B*S = 8192

DEV unsigned short f2bf(float f) {
  union { float f; unsigned int u; } v; v.f = f;
  unsigned int u = v.u;
  unsigned int r = u + 0x7fffu + ((u >> 16) & 1u);
  return (unsigned short)(r >> 16);
}

// packed fp32x2 -> bf16x2 via the HW instruction (T12 recipe; no builtin on gfx950)
DEV unsigned int pkbf(float lo, float hi) {
  unsigned int r;
  asm("v_cvt_pk_bf16_f32 %0, %1, %2" : "=v"(r) : "v"(lo), "v"(hi));
  return r;
}

DEV float fexp2(float x) { return __builtin_amdgcn_exp2f(x); }  // raw v_exp_f32

DEV void gload_lds16(const void* g, void* l) {
  __builtin_amdgcn_global_load_lds(
      (const __attribute__((address_space(1))) unsigned int*)g,
      (__attribute__((address_space(3))) unsigned int*)l, 16, 0, 0);
}

// ---------------- fp32 -> bf16 convert (x) ----------------
__global__ __launch_bounds__(256) void k_conv(const float* __restrict__ in,
                                              unsigned short* __restrict__ out) {
  int i = blockIdx.x * 256 + threadIdx.x;
  float4 v = ((const float4*)in)[i];
  ushort4 o;
  o.x = f2bf(v.x); o.y = f2bf(v.y); o.z = f2bf(v.z); o.w = f2bf(v.w);
  ((ushort4*)out)[i] = o;
}

// ---------------- transpose + convert all 4 weights (merged launch) ----------------
__global__ __launch_bounds__(256) void k_transpose4(const float* __restrict__ Wq,
                                                    const float* __restrict__ Wk,
                                                    const float* __restrict__ Wv,
                                                    const float* __restrict__ Wo,
                                                    unsigned short* __restrict__ wt,
                                                    unsigned short* __restrict__ wot) {
  __shared__ float tile[32][33];
  const int z = blockIdx.z;
  const float* W = (z == 0) ? Wq : (z == 1) ? Wk : (z == 2) ? Wv : Wo;
  unsigned short* Wt = (z == 3) ? wot : wt + (size_t)z * DMODEL * DMODEL;
  int n0 = blockIdx.x * 32, k0 = blockIdx.y * 32;
  int tx = threadIdx.x, ty = threadIdx.y;  // (32,8)
#pragma unroll
  for (int j = 0; j < 4; ++j)
    tile[ty + j * 8][tx] = W[(size_t)(k0 + ty + j * 8) * DMODEL + n0 + tx];
  __syncthreads();
#pragma unroll
  for (int j = 0; j < 4; ++j)
    Wt[(size_t)(n0 + ty + j * 8) * DMODEL + k0 + tx] = f2bf(tile[tx][ty + j * 8]);
}

// ---------------- counted-vmcnt double-buffered GEMM (T3+T4+T5+T2) ----------------
// BM=256, BN=128, BK=64, 512 thr = 8 waves (4M x 2N), per-wave 64x64 output.
// EPI=0: scatter bf16 to Q/K/V (B,H,S,HD); Q pre-scaled by 0.125/ln2 (exp2 trick).
// EPI=1: fp32 out = acc + bo[n].
template<int NBX, int EPI>
__global__ __launch_bounds__(512, 2) void k_gemm8(const unsigned short* __restrict__ A,
                                                  const unsigned short* __restrict__ Bt,
                                                  unsigned short* __restrict__ Qg,
                                                  unsigned short* __restrict__ Kg,
                                                  unsigned short* __restrict__ Vg,
                                                  const float* __restrict__ bo,
                                                  float* __restrict__ out) {
  __shared__ __align__(16) char lds[98304];
  const int tid = threadIdx.x, lane = tid & 63;
  const int wid = tid >> 6, wm = wid >> 1, wn = wid & 1;
  const int lq = lane & 15, lg = lane >> 4;
  const int flat = blockIdx.x;
  const int wg = (flat & 7) * (NBX * 4) + (flat >> 3);
  const int by = wg / NBX, bx = wg % NBX;
  const int m0 = by * 256, n0 = bx * 128;

  auto stage = [&](int kt, int buf) {
    char* dA = lds + buf * 49152;
    char* dB = dA + 32768;
    const unsigned short* gA = A + (size_t)m0 * DMODEL + kt * 64;
    const unsigned short* gB = Bt + (size_t)n0 * DMODEL + kt * 64;
#pragma unroll
    for (int i = 0; i < 4; ++i) {
      int c = tid + i * 512; int r = c >> 3, cc = c & 7;
      gload_lds16(gA + (size_t)r * DMODEL + ((cc ^ (r & 7)) << 3), dA + c * 16);
    }
#pragma unroll
    for (int i = 0; i < 2; ++i) {
      int c = tid + i * 512; int r = c >> 3, cc = c & 7;
      gload_lds16(gB + (size_t)r * DMODEL + ((cc ^ (r & 7)) << 3), dB + c * 16);
    }
  };

  stage(0, 0);
  stage(1, 1);
  SCHED0;
  asm volatile("s_waitcnt vmcnt(6)" ::: "memory");
  SCHED0;
  SBAR;
  SCHED0;

  f32x4 acc[4][4] = {};
#pragma unroll 1
  for (int t = 0; t < 16; ++t) {
    const int cur = t & 1;
    const char* pA = lds + cur * 49152;
    const char* pB = pA + 32768;
    bf16x8 af[4][2], bf[4][2];
#pragma unroll
    for (int kk = 0; kk < 2; ++kk) {
#pragma unroll
      for (int mi = 0; mi < 4; ++mi) {
        int row = wm * 64 + mi * 16 + lq;
        af[mi][kk] = *(const bf16x8*)(pA + row * 128 + ((((kk << 2) + lg) ^ (row & 7)) << 4));
      }
#pragma unroll
      for (int ni = 0; ni < 4; ++ni) {
        int row = wn * 64 + ni * 16 + lq;
        bf[ni][kk] = *(const bf16x8*)(pB + row * 128 + ((((kk << 2) + lg) ^ (row & 7)) << 4));
      }
    }
    asm volatile("s_waitcnt lgkmcnt(0)" ::: "memory");
    SCHED0;
    SBAR;
    SCHED0;
    if (t < 14) stage(t + 2, cur);
    __builtin_amdgcn_s_setprio(1);
#pragma unroll
    for (int kk = 0; kk < 2; ++kk)
#pragma unroll
      for (int mi = 0; mi < 4; ++mi)
#pragma unroll
        for (int ni = 0; ni < 4; ++ni)
          acc[mi][ni] = MFMA16(af[mi][kk], bf[ni][kk], acc[mi][ni], 0, 0, 0);
    __builtin_amdgcn_s_setprio(0);
    SCHED0;
    if (t < 14) {
      asm volatile("s_waitcnt vmcnt(6)" ::: "memory");
    } else if (t == 14) {
      asm volatile("s_waitcnt vmcnt(0)" ::: "memory");
    }
    SCHED0;
    SBAR;
    SCHED0;
  }

  if (EPI == 0) {
#pragma unroll
    for (int mi = 0; mi < 4; ++mi)
#pragma unroll
      for (int ni = 0; ni < 4; ++ni) {
        int n = n0 + wn * 64 + ni * 16 + lq;
        int widx = n >> 10, nn = n & 1023;
        int h = nn >> 6, d = nn & 63;
        unsigned short* dst = (widx == 0) ? Qg : ((widx == 1) ? Kg : Vg);
        float scale = (widx == 0) ? 0.18033688f : 1.0f;
#pragma unroll
        for (int r = 0; r < 4; ++r) {
          int m = m0 + wm * 64 + mi * 16 + lg * 4 + r;
          int b_ = m >> 11, s_ = m & 2047;
          dst[(size_t)((b_ * 16 + h) * 2048 + s_) * HD + d] = f2bf(acc[mi][ni][r] * scale);
        }
      }
  } else {
#pragma unroll
    for (int mi = 0; mi < 4; ++mi)
#pragma unroll
      for (int ni = 0; ni < 4; ++ni) {
        int n = n0 + wn * 64 + ni * 16 + lq;
        float bv = bo[n];
#pragma unroll
        for (int r = 0; r < 4; ++r) {
          int m = m0 + wm * 64 + mi * 16 + lg * 4 + r;
          out[(size_t)m * DMODEL + n] = acc[mi][ni][r] + bv;
        }
      }
  }
}

// ---------------- causal flash attention: swapped-QK^T, in-register softmax ----------------
// ROUND-4 PROVEN STRUCTURE (82.8us): 8 waves x 32 q-rows = 256-row blocks;
// pairs (p, 7-p) -> uniform 36 tile-iters; grid (4,64) = 256 blocks = 1/CU.
// NO setprio (lockstep waves: m190 regime). Scores in log2 units -> raw v_exp_f32.
// P-pack via HW v_cvt_pk_bf16_f32.
__global__ __launch_bounds__(512, 2) void k_attn(const unsigned short* __restrict__ Qg,
                                                 const unsigned short* __restrict__ Kg,
                                                 const unsigned short* __restrict__ Vg,
                                                 unsigned short* __restrict__ Ctx) {
  // [0,8K): sK buf0  [8K,16K): sK buf1  [16K,24K): sVT buf0  [24K,32K): sVT buf1
  __shared__ __align__(16) char lds[32768];
  const int pr = blockIdx.x;          // 0..3
  const int bh = blockIdx.y;
  const int tid = threadIdx.x;
  const int lane = tid & 63, w = tid >> 6;
  const int lq5 = lane & 31, hi = lane >> 5;
  const size_t base = (size_t)bh * (S * HD);
  const int b = bh >> 4, h = bh & 15;
  const int vkrow = tid >> 3, vcc = tid & 7;   // V staging: chunk tid = V[krow][cc*8..+7]

#pragma unroll 1
  for (int half = 0; half < 2; ++half) {
    const int Qb = half ? (7 - pr) : pr;
    const int q0w = Qb * 256 + w * 32;
    const int tmax = 4 * Qb + 3;
    const int diag = q0w >> 6;

    bf16x8 qF[4];
#pragma unroll
    for (int dc = 0; dc < 4; ++dc)
      qF[dc] = *(const bf16x8*)(Qg + base + (size_t)(q0w + lq5) * HD + dc * 16 + hi * 8);

    f32x16 o0 = {}, o1 = {};
    float m_run = -INFINITY, l_run = 0.f;

    __syncthreads();   // protect LDS from previous half's epilogue reads
    // prologue: stage tile 0 into buf0
    {
      int row = tid >> 3, cc = tid & 7, scc = cc ^ (row & 7);
      gload_lds16(Kg + base + (size_t)row * HD + scc * 8, lds + tid * 16);
      bf16x8 vv = *(const bf16x8*)(Vg + base + (size_t)vkrow * HD + vcc * 8);
#pragma unroll
      for (int j = 0; j < 8; ++j) {
        int d = vcc * 8 + j;
        int fd = (d & 7) ^ ((d >> 3) & 7);
        *(unsigned short*)(lds + 16384 + d * 128 + (((vkrow >> 3) ^ fd) << 4) + (vkrow & 7) * 2) =
            (unsigned short)vv[j];
      }
    }
    __syncthreads();

#pragma unroll 1
    for (int t = 0; t <= tmax; ++t) {
      const int cur = t & 1, nxt = cur ^ 1;
      char* sK  = lds + cur * 8192;
      char* sVT = lds + 16384 + cur * 8192;
      const bool have_next = (t < tmax);
      bf16x8 vv;
      if (have_next) {   // T14: issue next-tile loads EARLY
        vv = *(const bf16x8*)(Vg + base + (size_t)((t + 1) * 64 + vkrow) * HD + vcc * 8);
        int row = tid >> 3, cc = tid & 7, scc = cc ^ (row & 7);
        gload_lds16(Kg + base + (size_t)((t + 1) * 64 + row) * HD + scc * 8,
                    lds + nxt * 8192 + tid * 16);
      }
      const bool active = (t <= diag);
      if (active) {
        const bool isdiag = (t == diag);
        const int nkb = (isdiag && !(q0w & 32)) ? 1 : 2;
        // ---- QK^T swapped: st[k][q], scores in log2 units ----
        f32x16 st0 = {}, st1 = {};
#pragma unroll
        for (int dc = 0; dc < 4; ++dc) {
          int row = lq5;
          bf16x8 a0 = *(const bf16x8*)(sK + row * 128 + (((2 * dc + hi) ^ (row & 7)) << 4));
          st0 = MFMA32(a0, qF[dc], st0, 0, 0, 0);
        }
        if (nkb == 2) {
#pragma unroll
          for (int dc = 0; dc < 4; ++dc) {
            int row = 32 + lq5;
            bf16x8 a1 = *(const bf16x8*)(sK + row * 128 + (((2 * dc + hi) ^ (row & 7)) << 4));
            st1 = MFMA32(a1, qF[dc], st1, 0, 0, 0);
          }
        }
        // ---- mask (diagonal tile only) ----
        if (isdiag) {
          int qo = q0w + lq5 - t * 64;
          if (q0w & 32) {
#pragma unroll
            for (int r = 0; r < 16; ++r) {
              int key = 32 + (r & 3) + 8 * (r >> 2) + 4 * hi;
              st1[r] = (key > qo) ? -INFINITY : st1[r];
            }
          } else {
#pragma unroll
            for (int r = 0; r < 16; ++r) {
              int key = (r & 3) + 8 * (r >> 2) + 4 * hi;
              st0[r] = (key > qo) ? -INFINITY : st0[r];
            }
          }
        }
        // ---- row max: in-lane tree + one cross-pair swap ----
        float mx = st0[0];
#pragma unroll
        for (int r = 1; r < 16; ++r) mx = fmaxf(mx, st0[r]);
        if (nkb == 2) {
#pragma unroll
          for (int r = 0; r < 16; ++r) mx = fmaxf(mx, st1[r]);
        }
        mx = fmaxf(mx, __shfl_xor(mx, 32));
        // ---- defer-max (T13, THR=8 in log2 units -> P <= 256) ----
        bool need = !(mx <= m_run + 8.0f);
        if (__any(need)) {
          float mn = fmaxf(m_run, mx);
          float alpha = fexp2(m_run - mn);
          m_run = mn;
          l_run *= alpha;
#pragma unroll
          for (int r = 0; r < 16; ++r) { o0[r] *= alpha; o1[r] *= alpha; }
        }
        // ---- exp2 + row sum ----
        float rs[4] = {0.f, 0.f, 0.f, 0.f};
#pragma unroll
        for (int r = 0; r < 16; ++r) {
          float p = fexp2(st0[r] - m_run);
          st0[r] = p;
          rs[r & 3] += p;
        }
        if (nkb == 2) {
#pragma unroll
          for (int r = 0; r < 16; ++r) {
            float p = fexp2(st1[r] - m_run);
            st1[r] = p;
            rs[r & 3] += p;
          }
        }
        float rsum = (rs[0] + rs[1]) + (rs[2] + rs[3]);
        rsum += __shfl_xor(rsum, 32);
        l_run += rsum;
        // ---- P -> bf16 B-frags via cvt_pk + permlane32_swap (T12); PV: O^T += V^T.P^T ----
        {
          unsigned int wv[8];
#pragma unroll
          for (int j = 0; j < 8; ++j) wv[j] = pkbf(st0[2 * j], st0[2 * j + 1]);
          asm("v_permlane32_swap_b32 %0, %1" : "+v"(wv[0]), "+v"(wv[2]));
          asm("v_permlane32_swap_b32 %0, %1" : "+v"(wv[1]), "+v"(wv[3]));
          asm("v_permlane32_swap_b32 %0, %1" : "+v"(wv[4]), "+v"(wv[6]));
          asm("v_permlane32_swap_b32 %0, %1" : "+v"(wv[5]), "+v"(wv[7]));
          union { bf16x8 v; unsigned int u[4]; } fa, fb;
          fa.u[0] = wv[0]; fa.u[1] = wv[1]; fa.u[2] = wv[2]; fa.u[3] = wv[3];
          fb.u[0] = wv[4]; fb.u[1] = wv[5]; fb.u[2] = wv[6]; fb.u[3] = wv[7];
#pragma unroll
          for (int kc = 0; kc < 2; ++kc) {   // kc4 = kc (kb=0)
            bf16x8 bp = kc ? fb.v : fa.v;
            {
              int d = lq5, fd = (d & 7) ^ ((d >> 3) & 7);
              bf16x8 av = *(const bf16x8*)(sVT + d * 128 + (((kc * 2 + hi) ^ fd) << 4));
              o0 = MFMA32(av, bp, o0, 0, 0, 0);
            }
            {
              int d = 32 + lq5, fd = (d & 7) ^ ((d >> 3) & 7);
              bf16x8 av = *(const bf16x8*)(sVT + d * 128 + (((kc * 2 + hi) ^ fd) << 4));
              o1 = MFMA32(av, bp, o1, 0, 0, 0);
            }
          }
        }
        if (nkb == 2) {
          unsigned int wv[8];
#pragma unroll
          for (int j = 0; j < 8; ++j) wv[j] = pkbf(st1[2 * j], st1[2 * j + 1]);
          asm("v_permlane32_swap_b32 %0, %1" : "+v"(wv[0]), "+v"(wv[2]));
          asm("v_permlane32_swap_b32 %0, %1" : "+v"(wv[1]), "+v"(wv[3]));
          asm("v_permlane32_swap_b32 %0, %1" : "+v"(wv[4]), "+v"(wv[6]));
          asm("v_permlane32_swap_b32 %0, %1" : "+v"(wv[5]), "+v"(wv[7]));
          union { bf16x8 v; unsigned int u[4]; } fa, fb;
          fa.u[0] = wv[0]; fa.u[1] = wv[1]; fa.u[2] = wv[2]; fa.u[3] = wv[3];
          fb.u[0] = wv[4]; fb.u[1] = wv[5]; fb.u[2] = wv[6]; fb.u[3] = wv[7];
#pragma unroll
          for (int kc = 0; kc < 2; ++kc) {   // kc4 = 2 + kc (kb=1)
            bf16x8 bp = kc ? fb.v : fa.v;
            {
              int d = lq5, fd = (d & 7) ^ ((d >> 3) & 7);
              bf16x8 av = *(const bf16x8*)(sVT + d * 128 + ((((2 + kc) * 2 + hi) ^ fd) << 4));
              o0 = MFMA32(av, bp, o0, 0, 0, 0);
            }
            {
              int d = 32 + lq5, fd = (d & 7) ^ ((d >> 3) & 7);
              bf16x8 av = *(const bf16x8*)(sVT + d * 128 + ((((2 + kc) * 2 + hi) ^ fd) << 4));
              o1 = MFMA32(av, bp, o1, 0, 0, 0);
            }
          }
        }
      }
      // T14: write staged V LATE (vv HBM latency hidden under QK/softmax/PV)
      if (have_next) {
        char* dVT = lds + 16384 + nxt * 8192;
#pragma unroll
        for (int j = 0; j < 8; ++j) {
          int d = vcc * 8 + j;
          int fd = (d & 7) ^ ((d >> 3) & 7);
          *(unsigned short*)(dVT + d * 128 + (((vkrow >> 3) ^ fd) << 4) + (vkrow & 7) * 2) =
              (unsigned short)vv[j];
        }
      }
      __syncthreads();
    }

    // ---- epilogue: normalize, stage via LDS slice for coalesced stores ----
    __syncthreads();
    {
      float inv = 1.0f / l_run;
      char* slice = lds + w * 4096;   // [32 q][64 d] bf16, chunk-swizzled rows
#pragma unroll
      for (int db = 0; db < 2; ++db)
#pragma unroll
        for (int j = 0; j < 8; ++j) {
          int d0 = (j & 1) * 2 + (j >> 1) * 8 + 4 * hi + 32 * db;
          float va = (db ? o1[2 * j] : o0[2 * j]) * inv;
          float vb = (db ? o1[2 * j + 1] : o0[2 * j + 1]) * inv;
          *(unsigned int*)(slice + lq5 * 128 + (((d0 >> 3) ^ (lq5 & 7)) << 4) + (d0 & 7) * 2) =
              pkbf(va, vb);
        }
      asm volatile("s_waitcnt lgkmcnt(0)" ::: "memory");
#pragma unroll
      for (int i = 0; i < 4; ++i) {
        int r = lane >> 1, cc = (lane & 1) * 4 + i;
        u32x4 v = *(const u32x4*)(slice + r * 128 + ((cc ^ (r & 7)) << 4));
        *(u32x4*)(Ctx + (size_t)(b * S + q0w + r) * DMODEL + h * HD + cc * 8) = v;
      }
    }
  }
}

extern "C" void kernel_launch(void* const* d_in, const int* in_sizes, int n_in,
                              void* d_out, int out_size, void* d_ws, size_t ws_size,
                              hipStream_t stream) {
  const float* x  = (const float*)d_in[0];
  const float* Wq = (const float*)d_in[1];
  const float* Wk = (const float*)d_in[2];
  const float* Wv = (const float*)d_in[3];
  const float* Wo = (const float*)d_in[4];
  const float* bo = (const float*)d_in[5];
  float* out = (float*)d_out;

  char* p = (char*)d_ws;
  unsigned short* xb  = (unsigned short*)p; p += (size_t)MROWS * DMODEL * 2;
  unsigned short* wt  = (unsigned short*)p; p += (size_t)3 * DMODEL * DMODEL * 2;
  unsigned short* wot = (unsigned short*)p; p += (size_t)DMODEL * DMODEL * 2;
  unsigned short* qg  = (unsigned short*)p; p += (size_t)MROWS * DMODEL * 2;
  unsigned short* kg  = (unsigned short*)p; p += (size_t)MROWS * DMODEL * 2;
  unsigned short* vg  = (unsigned short*)p; p += (size_t)MROWS * DMODEL * 2;
  unsigned short* ctx = (unsigned short*)p; p += (size_t)MROWS * DMODEL * 2;

  k_conv<<<(MROWS * DMODEL) / 1024, 256, 0, stream>>>(x, xb);
  k_transpose4<<<dim3(32, 32, 4), dim3(32, 8), 0, stream>>>(Wq, Wk, Wv, Wo, wt, wot);
  k_gemm8<24, 0><<<768, 512, 0, stream>>>(xb, wt, qg, kg, vg, nullptr, nullptr);
  k_attn<<<dim3(4, 64), 512, 0, stream>>>(qg, kg, vg, ctx);
  k_gemm8<8, 1><<<256, 512, 0, stream>>>(ctx, wot, nullptr, nullptr, nullptr, bo, out);
}

// Round 9
// 178.204 us; speedup vs baseline: 1.7795x; 1.0076x over previous
//
#include <hip/hip_runtime.h>
#include <hip/hip_bf16.h>
#include <math.h>

typedef __attribute__((ext_vector_type(4))) float f32x4;
typedef __attribute__((ext_vector_type(16))) float f32x16;
typedef __attribute__((ext_vector_type(8))) short bf16x8;
typedef __attribute__((ext_vector_type(4))) unsigned int u32x4;

#define DEV __device__ __forceinline__
#define MFMA16 __builtin_amdgcn_mfma_f32_16x16x32_bf16
#define MFMA32 __builtin_amdgcn_mfma_f32_32x32x16_bf16
#define SBAR __builtin_amdgcn_s_barrier()
#define SCHED0 __builtin_amdgcn_sched_barrier(0)

constexpr int S      = 2048;
constexpr int DMODEL = 1024;
constexpr int HD     = 64;
constexpr int MROWS  = 4 * 2048;   // B*S = 8192

DEV unsigned short f2bf(float f) {
  union { float f; unsigned int u; } v; v.f = f;
  unsigned int u = v.u;
  unsigned int r = u + 0x7fffu + ((u >> 16) & 1u);
  return (unsigned short)(r >> 16);
}

// packed fp32x2 -> bf16x2 via the HW instruction (T12 recipe; no builtin on gfx950)
DEV unsigned int pkbf(float lo, float hi) {
  unsigned int r;
  asm("v_cvt_pk_bf16_f32 %0, %1, %2" : "=v"(r) : "v"(lo), "v"(hi));
  return r;
}

DEV float fexp2(float x) { return __builtin_amdgcn_exp2f(x); }  // raw v_exp_f32

DEV void gload_lds16(const void* g, void* l) {
  __builtin_amdgcn_global_load_lds(
      (const __attribute__((address_space(1))) unsigned int*)g,
      (__attribute__((address_space(3))) unsigned int*)l, 16, 0, 0);
}

// ---------------- fp32 -> bf16 convert (x) ----------------
__global__ __launch_bounds__(256) void k_conv(const float* __restrict__ in,
                                              unsigned short* __restrict__ out) {
  int i = blockIdx.x * 256 + threadIdx.x;
  float4 v = ((const float4*)in)[i];
  ushort4 o;
  o.x = f2bf(v.x); o.y = f2bf(v.y); o.z = f2bf(v.z); o.w = f2bf(v.w);
  ((ushort4*)out)[i] = o;
}

// ---------------- transpose + convert all 4 weights (merged launch) ----------------
__global__ __launch_bounds__(256) void k_transpose4(const float* __restrict__ Wq,
                                                    const float* __restrict__ Wk,
                                                    const float* __restrict__ Wv,
                                                    const float* __restrict__ Wo,
                                                    unsigned short* __restrict__ wt,
                                                    unsigned short* __restrict__ wot) {
  __shared__ float tile[32][33];
  const int z = blockIdx.z;
  const float* W = (z == 0) ? Wq : (z == 1) ? Wk : (z == 2) ? Wv : Wo;
  unsigned short* Wt = (z == 3) ? wot : wt + (size_t)z * DMODEL * DMODEL;
  int n0 = blockIdx.x * 32, k0 = blockIdx.y * 32;
  int tx = threadIdx.x, ty = threadIdx.y;  // (32,8)
#pragma unroll
  for (int j = 0; j < 4; ++j)
    tile[ty + j * 8][tx] = W[(size_t)(k0 + ty + j * 8) * DMODEL + n0 + tx];
  __syncthreads();
#pragma unroll
  for (int j = 0; j < 4; ++j)
    Wt[(size_t)(n0 + ty + j * 8) * DMODEL + k0 + tx] = f2bf(tile[tx][ty + j * 8]);
}

// ---------------- counted-vmcnt double-buffered GEMM (T3+T4+T5+T2) ----------------
// BM=256, BN=128, BK=64, 512 thr = 8 waves (4M x 2N), per-wave 64x64 output.
// EPI=0: scatter bf16 to Q/K/V (B,H,S,HD); Q pre-scaled by 0.125/ln2 (exp2 trick).
// EPI=1: fp32 out = acc + bo[n].
template<int NBX, int EPI>
__global__ __launch_bounds__(512, 2) void k_gemm8(const unsigned short* __restrict__ A,
                                                  const unsigned short* __restrict__ Bt,
                                                  unsigned short* __restrict__ Qg,
                                                  unsigned short* __restrict__ Kg,
                                                  unsigned short* __restrict__ Vg,
                                                  const float* __restrict__ bo,
                                                  float* __restrict__ out) {
  __shared__ __align__(16) char lds[98304];
  const int tid = threadIdx.x, lane = tid & 63;
  const int wid = tid >> 6, wm = wid >> 1, wn = wid & 1;
  const int lq = lane & 15, lg = lane >> 4;
  const int flat = blockIdx.x;
  const int wg = (flat & 7) * (NBX * 4) + (flat >> 3);
  const int by = wg / NBX, bx = wg % NBX;
  const int m0 = by * 256, n0 = bx * 128;

  auto stage = [&](int kt, int buf) {
    char* dA = lds + buf * 49152;
    char* dB = dA + 32768;
    const unsigned short* gA = A + (size_t)m0 * DMODEL + kt * 64;
    const unsigned short* gB = Bt + (size_t)n0 * DMODEL + kt * 64;
#pragma unroll
    for (int i = 0; i < 4; ++i) {
      int c = tid + i * 512; int r = c >> 3, cc = c & 7;
      gload_lds16(gA + (size_t)r * DMODEL + ((cc ^ (r & 7)) << 3), dA + c * 16);
    }
#pragma unroll
    for (int i = 0; i < 2; ++i) {
      int c = tid + i * 512; int r = c >> 3, cc = c & 7;
      gload_lds16(gB + (size_t)r * DMODEL + ((cc ^ (r & 7)) << 3), dB + c * 16);
    }
  };

  stage(0, 0);
  stage(1, 1);
  SCHED0;
  asm volatile("s_waitcnt vmcnt(6)" ::: "memory");
  SCHED0;
  SBAR;
  SCHED0;

  f32x4 acc[4][4] = {};
#pragma unroll 1
  for (int t = 0; t < 16; ++t) {
    const int cur = t & 1;
    const char* pA = lds + cur * 49152;
    const char* pB = pA + 32768;
    bf16x8 af[4][2], bf[4][2];
#pragma unroll
    for (int kk = 0; kk < 2; ++kk) {
#pragma unroll
      for (int mi = 0; mi < 4; ++mi) {
        int row = wm * 64 + mi * 16 + lq;
        af[mi][kk] = *(const bf16x8*)(pA + row * 128 + ((((kk << 2) + lg) ^ (row & 7)) << 4));
      }
#pragma unroll
      for (int ni = 0; ni < 4; ++ni) {
        int row = wn * 64 + ni * 16 + lq;
        bf[ni][kk] = *(const bf16x8*)(pB + row * 128 + ((((kk << 2) + lg) ^ (row & 7)) << 4));
      }
    }
    asm volatile("s_waitcnt lgkmcnt(0)" ::: "memory");
    SCHED0;
    SBAR;
    SCHED0;
    if (t < 14) stage(t + 2, cur);
    __builtin_amdgcn_s_setprio(1);
#pragma unroll
    for (int kk = 0; kk < 2; ++kk)
#pragma unroll
      for (int mi = 0; mi < 4; ++mi)
#pragma unroll
        for (int ni = 0; ni < 4; ++ni)
          acc[mi][ni] = MFMA16(af[mi][kk], bf[ni][kk], acc[mi][ni], 0, 0, 0);
    __builtin_amdgcn_s_setprio(0);
    SCHED0;
    if (t < 14) {
      asm volatile("s_waitcnt vmcnt(6)" ::: "memory");
    } else if (t == 14) {
      asm volatile("s_waitcnt vmcnt(0)" ::: "memory");
    }
    SCHED0;
    SBAR;
    SCHED0;
  }

  if (EPI == 0) {
#pragma unroll
    for (int mi = 0; mi < 4; ++mi)
#pragma unroll
      for (int ni = 0; ni < 4; ++ni) {
        int n = n0 + wn * 64 + ni * 16 + lq;
        int widx = n >> 10, nn = n & 1023;
        int h = nn >> 6, d = nn & 63;
        unsigned short* dst = (widx == 0) ? Qg : ((widx == 1) ? Kg : Vg);
        float scale = (widx == 0) ? 0.18033688f : 1.0f;
#pragma unroll
        for (int r = 0; r < 4; ++r) {
          int m = m0 + wm * 64 + mi * 16 + lg * 4 + r;
          int b_ = m >> 11, s_ = m & 2047;
          dst[(size_t)((b_ * 16 + h) * 2048 + s_) * HD + d] = f2bf(acc[mi][ni][r] * scale);
        }
      }
  } else {
#pragma unroll
    for (int mi = 0; mi < 4; ++mi)
#pragma unroll
      for (int ni = 0; ni < 4; ++ni) {
        int n = n0 + wn * 64 + ni * 16 + lq;
        float bv = bo[n];
#pragma unroll
        for (int r = 0; r < 4; ++r) {
          int m = m0 + wm * 64 + mi * 16 + lg * 4 + r;
          out[(size_t)m * DMODEL + n] = acc[mi][ni][r] + bv;
        }
      }
  }
}

// ---------------- causal flash attention: swapped-QK^T, in-register softmax ----------------
// Round-8 inner code, half-loop hoisted to grid: 512 blocks (one Qb each, 256 q-rows,
// 8 waves x 32 rows) = 2 independent blocks/CU = 4 waves/SIMD, SAME total K/V stream
// (144 tiles/bh). Flat-id mapping pairs Qb=q with Qb=7-q at grid offset +256 so
// round-robin dispatch lands balanced per-CU loads. Scores in log2 units.
__global__ __launch_bounds__(512, 2) void k_attn(const unsigned short* __restrict__ Qg,
                                                 const unsigned short* __restrict__ Kg,
                                                 const unsigned short* __restrict__ Vg,
                                                 unsigned short* __restrict__ Ctx) {
  // [0,8K): sK buf0  [8K,16K): sK buf1  [16K,24K): sVT buf0  [24K,32K): sVT buf1
  __shared__ __align__(16) char lds[32768];
  const int f = blockIdx.x;           // 0..511
  const int i4 = f & 255, hi2 = f >> 8;
  const int bh = i4 >> 2, q = i4 & 3;
  const int Qb = hi2 ? (7 - q) : q;
  const int tid = threadIdx.x;
  const int lane = tid & 63, w = tid >> 6;
  const int lq5 = lane & 31, hi = lane >> 5;
  const size_t base = (size_t)bh * (S * HD);
  const int b = bh >> 4, h = bh & 15;
  const int vkrow = tid >> 3, vcc = tid & 7;   // V staging: chunk tid = V[krow][cc*8..+7]

  const int q0w = Qb * 256 + w * 32;
  const int tmax = 4 * Qb + 3;
  const int diag = q0w >> 6;

  bf16x8 qF[4];
#pragma unroll
  for (int dc = 0; dc < 4; ++dc)
    qF[dc] = *(const bf16x8*)(Qg + base + (size_t)(q0w + lq5) * HD + dc * 16 + hi * 8);

  f32x16 o0 = {}, o1 = {};
  float m_run = -INFINITY, l_run = 0.f;

  // prologue: stage tile 0 into buf0
  {
    int row = tid >> 3, cc = tid & 7, scc = cc ^ (row & 7);
    gload_lds16(Kg + base + (size_t)row * HD + scc * 8, lds + tid * 16);
    bf16x8 vv = *(const bf16x8*)(Vg + base + (size_t)vkrow * HD + vcc * 8);
#pragma unroll
    for (int j = 0; j < 8; ++j) {
      int d = vcc * 8 + j;
      int fd = (d & 7) ^ ((d >> 3) & 7);
      *(unsigned short*)(lds + 16384 + d * 128 + (((vkrow >> 3) ^ fd) << 4) + (vkrow & 7) * 2) =
          (unsigned short)vv[j];
    }
  }
  __syncthreads();

#pragma unroll 1
  for (int t = 0; t <= tmax; ++t) {
    const int cur = t & 1, nxt = cur ^ 1;
    char* sK  = lds + cur * 8192;
    char* sVT = lds + 16384 + cur * 8192;
    const bool have_next = (t < tmax);
    bf16x8 vv;
    if (have_next) {   // T14: issue next-tile loads EARLY
      vv = *(const bf16x8*)(Vg + base + (size_t)((t + 1) * 64 + vkrow) * HD + vcc * 8);
      int row = tid >> 3, cc = tid & 7, scc = cc ^ (row & 7);
      gload_lds16(Kg + base + (size_t)((t + 1) * 64 + row) * HD + scc * 8,
                  lds + nxt * 8192 + tid * 16);
    }
    const bool active = (t <= diag);
    if (active) {
      const bool isdiag = (t == diag);
      const int nkb = (isdiag && !(q0w & 32)) ? 1 : 2;
      // ---- QK^T swapped: st[k][q], scores in log2 units ----
      f32x16 st0 = {}, st1 = {};
#pragma unroll
      for (int dc = 0; dc < 4; ++dc) {
        int row = lq5;
        bf16x8 a0 = *(const bf16x8*)(sK + row * 128 + (((2 * dc + hi) ^ (row & 7)) << 4));
        st0 = MFMA32(a0, qF[dc], st0, 0, 0, 0);
      }
      if (nkb == 2) {
#pragma unroll
        for (int dc = 0; dc < 4; ++dc) {
          int row = 32 + lq5;
          bf16x8 a1 = *(const bf16x8*)(sK + row * 128 + (((2 * dc + hi) ^ (row & 7)) << 4));
          st1 = MFMA32(a1, qF[dc], st1, 0, 0, 0);
        }
      }
      // ---- mask (diagonal tile only) ----
      if (isdiag) {
        int qo = q0w + lq5 - t * 64;
        if (q0w & 32) {
#pragma unroll
          for (int r = 0; r < 16; ++r) {
            int key = 32 + (r & 3) + 8 * (r >> 2) + 4 * hi;
            st1[r] = (key > qo) ? -INFINITY : st1[r];
          }
        } else {
#pragma unroll
          for (int r = 0; r < 16; ++r) {
            int key = (r & 3) + 8 * (r >> 2) + 4 * hi;
            st0[r] = (key > qo) ? -INFINITY : st0[r];
          }
        }
      }
      // ---- row max: in-lane tree + one cross-pair swap ----
      float mx = st0[0];
#pragma unroll
      for (int r = 1; r < 16; ++r) mx = fmaxf(mx, st0[r]);
      if (nkb == 2) {
#pragma unroll
        for (int r = 0; r < 16; ++r) mx = fmaxf(mx, st1[r]);
      }
      mx = fmaxf(mx, __shfl_xor(mx, 32));
      // ---- defer-max (T13, THR=8 in log2 units -> P <= 256) ----
      bool need = !(mx <= m_run + 8.0f);
      if (__any(need)) {
        float mn = fmaxf(m_run, mx);
        float alpha = fexp2(m_run - mn);
        m_run = mn;
        l_run *= alpha;
#pragma unroll
        for (int r = 0; r < 16; ++r) { o0[r] *= alpha; o1[r] *= alpha; }
      }
      // ---- exp2 + row sum ----
      float rs[4] = {0.f, 0.f, 0.f, 0.f};
#pragma unroll
      for (int r = 0; r < 16; ++r) {
        float p = fexp2(st0[r] - m_run);
        st0[r] = p;
        rs[r & 3] += p;
      }
      if (nkb == 2) {
#pragma unroll
        for (int r = 0; r < 16; ++r) {
          float p = fexp2(st1[r] - m_run);
          st1[r] = p;
          rs[r & 3] += p;
        }
      }
      float rsum = (rs[0] + rs[1]) + (rs[2] + rs[3]);
      rsum += __shfl_xor(rsum, 32);
      l_run += rsum;
      // ---- P -> bf16 B-frags via cvt_pk + permlane32_swap (T12); PV: O^T += V^T.P^T ----
      {
        unsigned int wv[8];
#pragma unroll
        for (int j = 0; j < 8; ++j) wv[j] = pkbf(st0[2 * j], st0[2 * j + 1]);
        asm("v_permlane32_swap_b32 %0, %1" : "+v"(wv[0]), "+v"(wv[2]));
        asm("v_permlane32_swap_b32 %0, %1" : "+v"(wv[1]), "+v"(wv[3]));
        asm("v_permlane32_swap_b32 %0, %1" : "+v"(wv[4]), "+v"(wv[6]));
        asm("v_permlane32_swap_b32 %0, %1" : "+v"(wv[5]), "+v"(wv[7]));
        union { bf16x8 v; unsigned int u[4]; } fa, fb;
        fa.u[0] = wv[0]; fa.u[1] = wv[1]; fa.u[2] = wv[2]; fa.u[3] = wv[3];
        fb.u[0] = wv[4]; fb.u[1] = wv[5]; fb.u[2] = wv[6]; fb.u[3] = wv[7];
#pragma unroll
        for (int kc = 0; kc < 2; ++kc) {   // kc4 = kc (kb=0)
          bf16x8 bp = kc ? fb.v : fa.v;
          {
            int d = lq5, fd = (d & 7) ^ ((d >> 3) & 7);
            bf16x8 av = *(const bf16x8*)(sVT + d * 128 + (((kc * 2 + hi) ^ fd) << 4));
            o0 = MFMA32(av, bp, o0, 0, 0, 0);
          }
          {
            int d = 32 + lq5, fd = (d & 7) ^ ((d >> 3) & 7);
            bf16x8 av = *(const bf16x8*)(sVT + d * 128 + (((kc * 2 + hi) ^ fd) << 4));
            o1 = MFMA32(av, bp, o1, 0, 0, 0);
          }
        }
      }
      if (nkb == 2) {
        unsigned int wv[8];
#pragma unroll
        for (int j = 0; j < 8; ++j) wv[j] = pkbf(st1[2 * j], st1[2 * j + 1]);
        asm("v_permlane32_swap_b32 %0, %1" : "+v"(wv[0]), "+v"(wv[2]));
        asm("v_permlane32_swap_b32 %0, %1" : "+v"(wv[1]), "+v"(wv[3]));
        asm("v_permlane32_swap_b32 %0, %1" : "+v"(wv[4]), "+v"(wv[6]));
        asm("v_permlane32_swap_b32 %0, %1" : "+v"(wv[5]), "+v"(wv[7]));
        union { bf16x8 v; unsigned int u[4]; } fa, fb;
        fa.u[0] = wv[0]; fa.u[1] = wv[1]; fa.u[2] = wv[2]; fa.u[3] = wv[3];
        fb.u[0] = wv[4]; fb.u[1] = wv[5]; fb.u[2] = wv[6]; fb.u[3] = wv[7];
#pragma unroll
        for (int kc = 0; kc < 2; ++kc) {   // kc4 = 2 + kc (kb=1)
          bf16x8 bp = kc ? fb.v : fa.v;
          {
            int d = lq5, fd = (d & 7) ^ ((d >> 3) & 7);
            bf16x8 av = *(const bf16x8*)(sVT + d * 128 + ((((2 + kc) * 2 + hi) ^ fd) << 4));
            o0 = MFMA32(av, bp, o0, 0, 0, 0);
          }
          {
            int d = 32 + lq5, fd = (d & 7) ^ ((d >> 3) & 7);
            bf16x8 av = *(const bf16x8*)(sVT + d * 128 + ((((2 + kc) * 2 + hi) ^ fd) << 4));
            o1 = MFMA32(av, bp, o1, 0, 0, 0);
          }
        }
      }
    }
    // T14: write staged V LATE (vv HBM latency hidden under QK/softmax/PV)
    if (have_next) {
      char* dVT = lds + 16384 + nxt * 8192;
#pragma unroll
      for (int j = 0; j < 8; ++j) {
        int d = vcc * 8 + j;
        int fd = (d & 7) ^ ((d >> 3) & 7);
        *(unsigned short*)(dVT + d * 128 + (((vkrow >> 3) ^ fd) << 4) + (vkrow & 7) * 2) =
            (unsigned short)vv[j];
      }
    }
    __syncthreads();
  }

  // ---- epilogue: normalize, stage via LDS slice for coalesced stores ----
  __syncthreads();
  {
    float inv = 1.0f / l_run;
    char* slice = lds + w * 4096;   // [32 q][64 d] bf16, chunk-swizzled rows
#pragma unroll
    for (int db = 0; db < 2; ++db)
#pragma unroll
      for (int j = 0; j < 8; ++j) {
        int d0 = (j & 1) * 2 + (j >> 1) * 8 + 4 * hi + 32 * db;
        float va = (db ? o1[2 * j] : o0[2 * j]) * inv;
        float vb = (db ? o1[2 * j + 1] : o0[2 * j + 1]) * inv;
        *(unsigned int*)(slice + lq5 * 128 + (((d0 >> 3) ^ (lq5 & 7)) << 4) + (d0 & 7) * 2) =
            pkbf(va, vb);
      }
    asm volatile("s_waitcnt lgkmcnt(0)" ::: "memory");
#pragma unroll
    for (int i = 0; i < 4; ++i) {
      int r = lane >> 1, cc = (lane & 1) * 4 + i;
      u32x4 v = *(const u32x4*)(slice + r * 128 + ((cc ^ (r & 7)) << 4));
      *(u32x4*)(Ctx + (size_t)(b * S + q0w + r) * DMODEL + h * HD + cc * 8) = v;
    }
  }
}

extern "C" void kernel_launch(void* const* d_in, const int* in_sizes, int n_in,
                              void* d_out, int out_size, void* d_ws, size_t ws_size,
                              hipStream_t stream) {
  const float* x  = (const float*)d_in[0];
  const float* Wq = (const float*)d_in[1];
  const float* Wk = (const float*)d_in[2];
  const float* Wv = (const float*)d_in[3];
  const float* Wo = (const float*)d_in[4];
  const float* bo = (const float*)d_in[5];
  float* out = (float*)d_out;

  char* p = (char*)d_ws;
  unsigned short* xb  = (unsigned short*)p; p += (size_t)MROWS * DMODEL * 2;
  unsigned short* wt  = (unsigned short*)p; p += (size_t)3 * DMODEL * DMODEL * 2;
  unsigned short* wot = (unsigned short*)p; p += (size_t)DMODEL * DMODEL * 2;
  unsigned short* qg  = (unsigned short*)p; p += (size_t)MROWS * DMODEL * 2;
  unsigned short* kg  = (unsigned short*)p; p += (size_t)MROWS * DMODEL * 2;
  unsigned short* vg  = (unsigned short*)p; p += (size_t)MROWS * DMODEL * 2;
  unsigned short* ctx = (unsigned short*)p; p += (size_t)MROWS * DMODEL * 2;

  k_conv<<<(MROWS * DMODEL) / 1024, 256, 0, stream>>>(x, xb);
  k_transpose4<<<dim3(32, 32, 4), dim3(32, 8), 0, stream>>>(Wq, Wk, Wv, Wo, wt, wot);
  k_gemm8<24, 0><<<768, 512, 0, stream>>>(xb, wt, qg, kg, vg, nullptr, nullptr);
  k_attn<<<512, 512, 0, stream>>>(qg, kg, vg, ctx);
  k_gemm8<8, 1><<<256, 512, 0, stream>>>(ctx, wot, nullptr, nullptr, nullptr, bo, out);
}

// Round 11
// 166.111 us; speedup vs baseline: 1.9091x; 1.0728x over previous
//
#include <hip/hip_runtime.h>
#include <hip/hip_bf16.h>
#include <math.h>

typedef __attribute__((ext_vector_type(4))) float f32x4;
typedef __attribute__((ext_vector_type(16))) float f32x16;
typedef __attribute__((ext_vector_type(8))) short bf16x8;
typedef __attribute__((ext_vector_type(4))) unsigned int u32x4;

#define DEV __device__ __forceinline__
#define MFMA16 __builtin_amdgcn_mfma_f32_16x16x32_bf16
#define MFMA32 __builtin_amdgcn_mfma_f32_32x32x16_bf16
#define SBAR __builtin_amdgcn_s_barrier()
#define SCHED0 __builtin_amdgcn_sched_barrier(0)

constexpr int S      = 2048;
constexpr int DMODEL = 1024;
constexpr int HD     = 64;
constexpr int MROWS  = 4 * 2048;   // B*S = 8192

DEV unsigned short f2bf(float f) {
  union { float f; unsigned int u; } v; v.f = f;
  unsigned int u = v.u;
  unsigned int r = u + 0x7fffu + ((u >> 16) & 1u);
  return (unsigned short)(r >> 16);
}

// packed fp32x2 -> bf16x2 via the HW instruction (T12 recipe; no builtin on gfx950)
DEV unsigned int pkbf(float lo, float hi) {
  unsigned int r;
  asm("v_cvt_pk_bf16_f32 %0, %1, %2" : "=v"(r) : "v"(lo), "v"(hi));
  return r;
}

DEV float fexp2(float x) { return __builtin_amdgcn_exp2f(x); }  // raw v_exp_f32

DEV void gload_lds16(const void* g, void* l) {
  __builtin_amdgcn_global_load_lds(
      (const __attribute__((address_space(1))) unsigned int*)g,
      (__attribute__((address_space(3))) unsigned int*)l, 16, 0, 0);
}

// ---------------- fp32 -> bf16 convert (x) ----------------
__global__ __launch_bounds__(256) void k_conv(const float* __restrict__ in,
                                              unsigned short* __restrict__ out) {
  int i = blockIdx.x * 256 + threadIdx.x;
  float4 v = ((const float4*)in)[i];
  ushort4 o;
  o.x = f2bf(v.x); o.y = f2bf(v.y); o.z = f2bf(v.z); o.w = f2bf(v.w);
  ((ushort4*)out)[i] = o;
}

// ---------------- transpose + convert all 4 weights (merged launch) ----------------
__global__ __launch_bounds__(256) void k_transpose4(const float* __restrict__ Wq,
                                                    const float* __restrict__ Wk,
                                                    const float* __restrict__ Wv,
                                                    const float* __restrict__ Wo,
                                                    unsigned short* __restrict__ wt,
                                                    unsigned short* __restrict__ wot) {
  __shared__ float tile[32][33];
  const int z = blockIdx.z;
  const float* W = (z == 0) ? Wq : (z == 1) ? Wk : (z == 2) ? Wv : Wo;
  unsigned short* Wt = (z == 3) ? wot : wt + (size_t)z * DMODEL * DMODEL;
  int n0 = blockIdx.x * 32, k0 = blockIdx.y * 32;
  int tx = threadIdx.x, ty = threadIdx.y;  // (32,8)
#pragma unroll
  for (int j = 0; j < 4; ++j)
    tile[ty + j * 8][tx] = W[(size_t)(k0 + ty + j * 8) * DMODEL + n0 + tx];
  __syncthreads();
#pragma unroll
  for (int j = 0; j < 4; ++j)
    Wt[(size_t)(n0 + ty + j * 8) * DMODEL + k0 + tx] = f2bf(tile[tx][ty + j * 8]);
}

// ---------------- counted-vmcnt double-buffered GEMM (T3+T4+T5+T2) ----------------
// BM=256, BN=128, BK=64, 512 thr = 8 waves (4M x 2N), per-wave 64x64 output.
// EPI=0: Q -> (B,H,S,HD) bf16 pre-scaled by 0.125/ln2; K -> (B,H,S,HD);
//        V -> TRANSPOSED Vt[(bh*64+d)*2048 + key] (ushort4 stores, key-contiguous).
// EPI=1: fp32 out = acc + bo[n].
template<int NBX, int EPI>
__global__ __launch_bounds__(512, 2) void k_gemm8(const unsigned short* __restrict__ A,
                                                  const unsigned short* __restrict__ Bt,
                                                  unsigned short* __restrict__ Qg,
                                                  unsigned short* __restrict__ Kg,
                                                  unsigned short* __restrict__ Vt,
                                                  const float* __restrict__ bo,
                                                  float* __restrict__ out) {
  __shared__ __align__(16) char lds[98304];
  const int tid = threadIdx.x, lane = tid & 63;
  const int wid = tid >> 6, wm = wid >> 1, wn = wid & 1;
  const int lq = lane & 15, lg = lane >> 4;
  const int flat = blockIdx.x;
  const int wg = (flat & 7) * (NBX * 4) + (flat >> 3);
  const int by = wg / NBX, bx = wg % NBX;
  const int m0 = by * 256, n0 = bx * 128;

  auto stage = [&](int kt, int buf) {
    char* dA = lds + buf * 49152;
    char* dB = dA + 32768;
    const unsigned short* gA = A + (size_t)m0 * DMODEL + kt * 64;
    const unsigned short* gB = Bt + (size_t)n0 * DMODEL + kt * 64;
#pragma unroll
    for (int i = 0; i < 4; ++i) {
      int c = tid + i * 512; int r = c >> 3, cc = c & 7;
      gload_lds16(gA + (size_t)r * DMODEL + ((cc ^ (r & 7)) << 3), dA + c * 16);
    }
#pragma unroll
    for (int i = 0; i < 2; ++i) {
      int c = tid + i * 512; int r = c >> 3, cc = c & 7;
      gload_lds16(gB + (size_t)r * DMODEL + ((cc ^ (r & 7)) << 3), dB + c * 16);
    }
  };

  stage(0, 0);
  stage(1, 1);
  SCHED0;
  asm volatile("s_waitcnt vmcnt(6)" ::: "memory");
  SCHED0;
  SBAR;
  SCHED0;

  f32x4 acc[4][4] = {};
#pragma unroll 1
  for (int t = 0; t < 16; ++t) {
    const int cur = t & 1;
    const char* pA = lds + cur * 49152;
    const char* pB = pA + 32768;
    bf16x8 af[4][2], bf[4][2];
#pragma unroll
    for (int kk = 0; kk < 2; ++kk) {
#pragma unroll
      for (int mi = 0; mi < 4; ++mi) {
        int row = wm * 64 + mi * 16 + lq;
        af[mi][kk] = *(const bf16x8*)(pA + row * 128 + ((((kk << 2) + lg) ^ (row & 7)) << 4));
      }
#pragma unroll
      for (int ni = 0; ni < 4; ++ni) {
        int row = wn * 64 + ni * 16 + lq;
        bf[ni][kk] = *(const bf16x8*)(pB + row * 128 + ((((kk << 2) + lg) ^ (row & 7)) << 4));
      }
    }
    asm volatile("s_waitcnt lgkmcnt(0)" ::: "memory");
    SCHED0;
    SBAR;
    SCHED0;
    if (t < 14) stage(t + 2, cur);
    __builtin_amdgcn_s_setprio(1);
#pragma unroll
    for (int kk = 0; kk < 2; ++kk)
#pragma unroll
      for (int mi = 0; mi < 4; ++mi)
#pragma unroll
        for (int ni = 0; ni < 4; ++ni)
          acc[mi][ni] = MFMA16(af[mi][kk], bf[ni][kk], acc[mi][ni], 0, 0, 0);
    __builtin_amdgcn_s_setprio(0);
    SCHED0;
    if (t < 14) {
      asm volatile("s_waitcnt vmcnt(6)" ::: "memory");
    } else if (t == 14) {
      asm volatile("s_waitcnt vmcnt(0)" ::: "memory");
    }
    SCHED0;
    SBAR;
    SCHED0;
  }

  if (EPI == 0) {
#pragma unroll
    for (int mi = 0; mi < 4; ++mi)
#pragma unroll
      for (int ni = 0; ni < 4; ++ni) {
        int n = n0 + wn * 64 + ni * 16 + lq;
        int widx = n >> 10, nn = n & 1023;
        int h = nn >> 6, d = nn & 63;
        int mbase = m0 + wm * 64 + mi * 16 + lg * 4;       // 4 consecutive rows
        int b_ = mbase >> 11, s_ = mbase & 2047;            // never crosses 2048 (s_%4==0)
        if (widx == 2) {
          ushort4 o;
          o.x = f2bf(acc[mi][ni][0]);
          o.y = f2bf(acc[mi][ni][1]);
          o.z = f2bf(acc[mi][ni][2]);
          o.w = f2bf(acc[mi][ni][3]);
          *(ushort4*)(Vt + ((size_t)((b_ * 16 + h) * 64 + d)) * S + s_) = o;
        } else {
          unsigned short* dst = (widx == 0) ? Qg : Kg;
          float scale = (widx == 0) ? 0.18033688f : 1.0f;
#pragma unroll
          for (int r = 0; r < 4; ++r)
            dst[(size_t)((b_ * 16 + h) * 2048 + s_ + r) * HD + d] = f2bf(acc[mi][ni][r] * scale);
        }
      }
  } else {
#pragma unroll
    for (int mi = 0; mi < 4; ++mi)
#pragma unroll
      for (int ni = 0; ni < 4; ++ni) {
        int n = n0 + wn * 64 + ni * 16 + lq;
        float bv = bo[n];
#pragma unroll
        for (int r = 0; r < 4; ++r) {
          int m = m0 + wm * 64 + mi * 16 + lg * 4 + r;
          out[(size_t)m * DMODEL + n] = acc[mi][ni][r] + bv;
        }
      }
  }
}

// ---------------- causal flash attention: swapped-QK^T, in-register softmax ----------------
// 512 blocks (one Qb each, 256 q-rows, 8 waves x 32). BOTH K and V^T staged by
// global_load_lds DMA (V read from pre-transposed Vt[bh][d][key]); PV reads use the
// r8-proven swizzled sVT formulas (swizzle realized via pre-swizzled DMA source,
// rule 21). Zero ds_writes in the main loop. Scores in log2 units.
__global__ __launch_bounds__(512, 2) void k_attn(const unsigned short* __restrict__ Qg,
                                                 const unsigned short* __restrict__ Kg,
                                                 const unsigned short* __restrict__ Vt,
                                                 unsigned short* __restrict__ Ctx) {
  // [0,8K)x2 = sK dbuf, [16K,24K)x2 = sVT dbuf ([d][key-chunk], fd-swizzled)
  __shared__ __align__(16) char lds[32768];
  const int f = blockIdx.x;           // 0..511
  const int i4 = f & 255, hi2 = f >> 8;
  const int bh = i4 >> 2, q = i4 & 3;
  const int Qb = hi2 ? (7 - q) : q;
  const int tid = threadIdx.x;
  const int lane = tid & 63, w = tid >> 6;
  const int lq5 = lane & 31, hi = lane >> 5;
  const size_t base = (size_t)bh * (S * HD);
  const int b = bh >> 4, h = bh & 15;
  // K staging: chunk tid -> K[krow][scc*8..+7] (pre-swizzled source)
  const int krow = tid >> 3, kcc = tid & 7, scc = kcc ^ (krow & 7);
  // V^T staging: row = d = tid>>3; source chunk pre-swizzled by fd(d) so that the
  // LDS content matches the r8 sVT layout exactly.
  const int vd = tid >> 3;
  const int vfd = (vd & 7) ^ ((vd >> 3) & 7);
  const int vscc = (tid & 7) ^ vfd;
  const unsigned short* VtRow = Vt + (size_t)(bh * 64 + vd) * S;

  const int q0w = Qb * 256 + w * 32;
  const int tmax = 4 * Qb + 3;
  const int diag = q0w >> 6;

  bf16x8 qF[4];
#pragma unroll
  for (int dc = 0; dc < 4; ++dc)
    qF[dc] = *(const bf16x8*)(Qg + base + (size_t)(q0w + lq5) * HD + dc * 16 + hi * 8);

  f32x16 o0 = {}, o1 = {};
  float m_run = -INFINITY, l_run = 0.f;

  // prologue: stage tile 0 (K + V^T, both DMA)
  gload_lds16(Kg + base + (size_t)krow * HD + scc * 8, lds + tid * 16);
  gload_lds16(VtRow + vscc * 8, lds + 16384 + tid * 16);
  __syncthreads();

#pragma unroll 1
  for (int t = 0; t <= tmax; ++t) {
    const int cur = t & 1, nxt = cur ^ 1;
    char* sK  = lds + cur * 8192;
    char* sVT = lds + 16384 + cur * 8192;
    const bool have_next = (t < tmax);
    if (have_next) {   // issue next-tile DMA EARLY; barrier at loop end drains
      gload_lds16(Kg + base + (size_t)((t + 1) * 64 + krow) * HD + scc * 8,
                  lds + nxt * 8192 + tid * 16);
      gload_lds16(VtRow + (t + 1) * 64 + vscc * 8,
                  lds + 16384 + nxt * 8192 + tid * 16);
    }
    const bool active = (t <= diag);
    if (active) {
      const bool isdiag = (t == diag);
      const int nkb = (isdiag && !(q0w & 32)) ? 1 : 2;
      // ---- QK^T swapped: st[k][q], scores in log2 units ----
      f32x16 st0 = {}, st1 = {};
#pragma unroll
      for (int dc = 0; dc < 4; ++dc) {
        int row = lq5;
        bf16x8 a0 = *(const bf16x8*)(sK + row * 128 + (((2 * dc + hi) ^ (row & 7)) << 4));
        st0 = MFMA32(a0, qF[dc], st0, 0, 0, 0);
      }
      if (nkb == 2) {
#pragma unroll
        for (int dc = 0; dc < 4; ++dc) {
          int row = 32 + lq5;
          bf16x8 a1 = *(const bf16x8*)(sK + row * 128 + (((2 * dc + hi) ^ (row & 7)) << 4));
          st1 = MFMA32(a1, qF[dc], st1, 0, 0, 0);
        }
      }
      // ---- mask (diagonal tile only) ----
      if (isdiag) {
        int qo = q0w + lq5 - t * 64;
        if (q0w & 32) {
#pragma unroll
          for (int r = 0; r < 16; ++r) {
            int key = 32 + (r & 3) + 8 * (r >> 2) + 4 * hi;
            st1[r] = (key > qo) ? -INFINITY : st1[r];
          }
        } else {
#pragma unroll
          for (int r = 0; r < 16; ++r) {
            int key = (r & 3) + 8 * (r >> 2) + 4 * hi;
            st0[r] = (key > qo) ? -INFINITY : st0[r];
          }
        }
      }
      // ---- row max: in-lane tree + one cross-pair swap ----
      float mx = st0[0];
#pragma unroll
      for (int r = 1; r < 16; ++r) mx = fmaxf(mx, st0[r]);
      if (nkb == 2) {
#pragma unroll
        for (int r = 0; r < 16; ++r) mx = fmaxf(mx, st1[r]);
      }
      mx = fmaxf(mx, __shfl_xor(mx, 32));
      // ---- defer-max (T13, THR=8 in log2 units -> P <= 256) ----
      bool need = !(mx <= m_run + 8.0f);
      if (__any(need)) {
        float mn = fmaxf(m_run, mx);
        float alpha = fexp2(m_run - mn);
        m_run = mn;
        l_run *= alpha;
#pragma unroll
        for (int r = 0; r < 16; ++r) { o0[r] *= alpha; o1[r] *= alpha; }
      }
      // ---- exp2 + row sum ----
      float rs[4] = {0.f, 0.f, 0.f, 0.f};
#pragma unroll
      for (int r = 0; r < 16; ++r) {
        float p = fexp2(st0[r] - m_run);
        st0[r] = p;
        rs[r & 3] += p;
      }
      if (nkb == 2) {
#pragma unroll
        for (int r = 0; r < 16; ++r) {
          float p = fexp2(st1[r] - m_run);
          st1[r] = p;
          rs[r & 3] += p;
        }
      }
      float rsum = (rs[0] + rs[1]) + (rs[2] + rs[3]);
      rsum += __shfl_xor(rsum, 32);
      l_run += rsum;
      // ---- P -> bf16 B-frags via cvt_pk + permlane32_swap (T12); PV: O^T += V^T.P^T ----
      {
        unsigned int wv[8];
#pragma unroll
        for (int j = 0; j < 8; ++j) wv[j] = pkbf(st0[2 * j], st0[2 * j + 1]);
        asm("v_permlane32_swap_b32 %0, %1" : "+v"(wv[0]), "+v"(wv[2]));
        asm("v_permlane32_swap_b32 %0, %1" : "+v"(wv[1]), "+v"(wv[3]));
        asm("v_permlane32_swap_b32 %0, %1" : "+v"(wv[4]), "+v"(wv[6]));
        asm("v_permlane32_swap_b32 %0, %1" : "+v"(wv[5]), "+v"(wv[7]));
        union { bf16x8 v; unsigned int u[4]; } fa, fb;
        fa.u[0] = wv[0]; fa.u[1] = wv[1]; fa.u[2] = wv[2]; fa.u[3] = wv[3];
        fb.u[0] = wv[4]; fb.u[1] = wv[5]; fb.u[2] = wv[6]; fb.u[3] = wv[7];
#pragma unroll
        for (int kc = 0; kc < 2; ++kc) {   // kc4 = kc (kb=0)
          bf16x8 bp = kc ? fb.v : fa.v;
          {
            int d = lq5, fd = (d & 7) ^ ((d >> 3) & 7);
            bf16x8 av = *(const bf16x8*)(sVT + d * 128 + (((kc * 2 + hi) ^ fd) << 4));
            o0 = MFMA32(av, bp, o0, 0, 0, 0);
          }
          {
            int d = 32 + lq5, fd = (d & 7) ^ ((d >> 3) & 7);
            bf16x8 av = *(const bf16x8*)(sVT + d * 128 + (((kc * 2 + hi) ^ fd) << 4));
            o1 = MFMA32(av, bp, o1, 0, 0, 0);
          }
        }
      }
      if (nkb == 2) {
        unsigned int wv[8];
#pragma unroll
        for (int j = 0; j < 8; ++j) wv[j] = pkbf(st1[2 * j], st1[2 * j + 1]);
        asm("v_permlane32_swap_b32 %0, %1" : "+v"(wv[0]), "+v"(wv[2]));
        asm("v_permlane32_swap_b32 %0, %1" : "+v"(wv[1]), "+v"(wv[3]));
        asm("v_permlane32_swap_b32 %0, %1" : "+v"(wv[4]), "+v"(wv[6]));
        asm("v_permlane32_swap_b32 %0, %1" : "+v"(wv[5]), "+v"(wv[7]));
        union { bf16x8 v; unsigned int u[4]; } fa, fb;
        fa.u[0] = wv[0]; fa.u[1] = wv[1]; fa.u[2] = wv[2]; fa.u[3] = wv[3];
        fb.u[0] = wv[4]; fb.u[1] = wv[5]; fb.u[2] = wv[6]; fb.u[3] = wv[7];
#pragma unroll
        for (int kc = 0; kc < 2; ++kc) {   // kc4 = 2 + kc (kb=1)
          bf16x8 bp = kc ? fb.v : fa.v;
          {
            int d = lq5, fd = (d & 7) ^ ((d >> 3) & 7);
            bf16x8 av = *(const bf16x8*)(sVT + d * 128 + ((((2 + kc) * 2 + hi) ^ fd) << 4));
            o0 = MFMA32(av, bp, o0, 0, 0, 0);
          }
          {
            int d = 32 + lq5, fd = (d & 7) ^ ((d >> 3) & 7);
            bf16x8 av = *(const bf16x8*)(sVT + d * 128 + ((((2 + kc) * 2 + hi) ^ fd) << 4));
            o1 = MFMA32(av, bp, o1, 0, 0, 0);
          }
        }
      }
    }
    __syncthreads();
  }

  // ---- epilogue: normalize, stage via per-wave LDS slice for coalesced stores ----
  __syncthreads();
  {
    float inv = 1.0f / l_run;
    char* slice = lds + w * 4096;   // [32 q][64 d] bf16, chunk-swizzled rows
#pragma unroll
    for (int db = 0; db < 2; ++db)
#pragma unroll
      for (int j = 0; j < 8; ++j) {
        int d0 = (j & 1) * 2 + (j >> 1) * 8 + 4 * hi + 32 * db;
        float va = (db ? o1[2 * j] : o0[2 * j]) * inv;
        float vb = (db ? o1[2 * j + 1] : o0[2 * j + 1]) * inv;
        *(unsigned int*)(slice + lq5 * 128 + (((d0 >> 3) ^ (lq5 & 7)) << 4) + (d0 & 7) * 2) =
            pkbf(va, vb);
      }
    asm volatile("s_waitcnt lgkmcnt(0)" ::: "memory");
#pragma unroll
    for (int i = 0; i < 4; ++i) {
      int r = lane >> 1, cc = (lane & 1) * 4 + i;
      u32x4 v = *(const u32x4*)(slice + r * 128 + ((cc ^ (r & 7)) << 4));
      *(u32x4*)(Ctx + (size_t)(b * S + q0w + r) * DMODEL + h * HD + cc * 8) = v;
    }
  }
}

extern "C" void kernel_launch(void* const* d_in, const int* in_sizes, int n_in,
                              void* d_out, int out_size, void* d_ws, size_t ws_size,
                              hipStream_t stream) {
  const float* x  = (const float*)d_in[0];
  const float* Wq = (const float*)d_in[1];
  const float* Wk = (const float*)d_in[2];
  const float* Wv = (const float*)d_in[3];
  const float* Wo = (const float*)d_in[4];
  const float* bo = (const float*)d_in[5];
  float* out = (float*)d_out;

  char* p = (char*)d_ws;
  unsigned short* xb  = (unsigned short*)p; p += (size_t)MROWS * DMODEL * 2;
  unsigned short* wt  = (unsigned short*)p; p += (size_t)3 * DMODEL * DMODEL * 2;
  unsigned short* wot = (unsigned short*)p; p += (size_t)DMODEL * DMODEL * 2;
  unsigned short* qg  = (unsigned short*)p; p += (size_t)MROWS * DMODEL * 2;
  unsigned short* kg  = (unsigned short*)p; p += (size_t)MROWS * DMODEL * 2;
  unsigned short* vt  = (unsigned short*)p; p += (size_t)MROWS * DMODEL * 2;  // Vt[bh][d][key]
  unsigned short* ctx = (unsigned short*)p; p += (size_t)MROWS * DMODEL * 2;

  k_conv<<<(MROWS * DMODEL) / 1024, 256, 0, stream>>>(x, xb);
  k_transpose4<<<dim3(32, 32, 4), dim3(32, 8), 0, stream>>>(Wq, Wk, Wv, Wo, wt, wot);
  k_gemm8<24, 0><<<768, 512, 0, stream>>>(xb, wt, qg, kg, vt, nullptr, nullptr);
  k_attn<<<512, 512, 0, stream>>>(qg, kg, vt, ctx);
  k_gemm8<8, 1><<<256, 512, 0, stream>>>(ctx, wot, nullptr, nullptr, nullptr, bo, out);
}